// Round 8
// baseline (456.513 us; speedup 1.0000x reference)
//
#include <hip/hip_runtime.h>
#include <math.h>

#define NN 50000
#define NE 400000
#define NG 128
#define SCAN_B 49   // ceil(NN/1024)

typedef __bf16 bf16x8 __attribute__((ext_vector_type(8)));
typedef float f32x4 __attribute__((ext_vector_type(4)));
typedef _Float16 h16x2 __attribute__((ext_vector_type(2)));
typedef _Float16 h16x4 __attribute__((ext_vector_type(4)));

// bijective XCD-chunked swizzle (m204): each XCD gets a contiguous chunk
__device__ __forceinline__ int xcd_swz(int bid, int nwg)
{
    int q = nwg >> 3, r = nwg & 7;
    int xcd = bid & 7, off = bid >> 3;
    return (xcd < r ? xcd * (q + 1) : r * (q + 1) + (xcd - r) * q) + off;
}

// ---------------------------------------------------------------------------
// prep: fused weights Wp1[64,128], Wp2[128,16]; concatenated biases
// ---------------------------------------------------------------------------
__global__ void prep_kernel(const float* __restrict__ Wq1, const float* __restrict__ bq1,
                            const float* __restrict__ bk1, const float* __restrict__ bv1,
                            const float* __restrict__ bs1, const float* __restrict__ We1,
                            const float* __restrict__ Wq2, const float* __restrict__ bq2,
                            const float* __restrict__ bk2, const float* __restrict__ bv2,
                            const float* __restrict__ bs2, const float* __restrict__ We2,
                            float* __restrict__ Wp1, float* __restrict__ Wp2,
                            float* __restrict__ bcat1, float* __restrict__ bcat2)
{
    int idx = blockIdx.x * blockDim.x + threadIdx.x;
    if (idx < 8192) {                       // Wp1[64,128]
        int m = idx >> 7, c = idx & 127;
        int h = c >> 4, d = c & 15;
        float s = 0.f;
        #pragma unroll
        for (int j = 0; j < 16; ++j)
            s += Wq1[m * 128 + h * 16 + j] * We1[d * 128 + h * 16 + j];
        Wp1[idx] = s;
    } else if (idx < 8320) {                // bp1 -> bcat1[512..640)
        int c = idx - 8192;
        int h = c >> 4, d = c & 15;
        float s = 0.f;
        #pragma unroll
        for (int j = 0; j < 16; ++j)
            s += bq1[h * 16 + j] * We1[d * 128 + h * 16 + j];
        bcat1[512 + c] = s;
    } else if (idx < 10368) {               // Wp2[128,16]
        int i = idx - 8320;
        int m = i >> 4, d = i & 15;
        float s = 0.f;
        for (int j = 0; j < 128; ++j)
            s += Wq2[m * 128 + j] * We2[d * 128 + j];
        Wp2[m * 16 + d] = s;
    } else if (idx < 10384) {               // bp2 -> bcat2[512..528)
        int d = idx - 10368;
        float s = 0.f;
        for (int j = 0; j < 128; ++j)
            s += bq2[j] * We2[d * 128 + j];
        bcat2[512 + d] = s;
    } else if (idx < 10896) {               // bcat1[0..512)
        int i = idx - 10384;
        int seg = i >> 7, c = i & 127;
        const float* b = (seg == 0) ? bq1 : (seg == 1) ? bk1 : (seg == 2) ? bv1 : bs1;
        bcat1[i] = b[c];
    } else if (idx < 11408) {               // bcat2[0..512)
        int i = idx - 10896;
        int seg = i >> 7, c = i & 127;
        const float* b = (seg == 0) ? bq2 : (seg == 1) ? bk2 : (seg == 2) ? bv2 : bs2;
        bcat2[i] = b[c];
    }
}

// ---------------------------------------------------------------------------
// pack: MFMA fragment-ready hi/lo bf16 weight blocks.
//   mat0: gemm1 Wcat[64,640]   blocks 0..79
//   mat1: gemm2 Wcat[128,528]  blocks 80..211
//   mat2: gemm3 Wcat[128,256]  blocks 212..275
//   mat3: W1c[16->32pad,128]   blocks 276..283 (for eaW GEMM)
// ---------------------------------------------------------------------------
__global__ void pack_kernel(const float* __restrict__ Wq1, const float* __restrict__ Wk1,
                            const float* __restrict__ Wv1, const float* __restrict__ Ws1,
                            const float* __restrict__ Wp1,
                            const float* __restrict__ Wq2, const float* __restrict__ Wk2,
                            const float* __restrict__ Wv2, const float* __restrict__ Ws2,
                            const float* __restrict__ Wp2,
                            const float* __restrict__ W1,
                            __bf16* __restrict__ pk)
{
    int b = blockIdx.x;
    int mat, kt, ct;
    if (b < 80)       { mat = 0; kt = b / 40;        ct = b % 40; }
    else if (b < 212) { mat = 1; kt = (b - 80) / 33; ct = (b - 80) % 33; }
    else if (b < 276) { mat = 2; kt = (b - 212) / 16; ct = (b - 212) % 16; }
    else              { mat = 3; kt = 0;             ct = b - 276; }
    __bf16* blkp = pk + (size_t)b * 1024;
    for (int item = threadIdx.x; item < 512; item += 256) {
        int lane = item >> 3, j = item & 7;
        int k = kt * 32 + (lane >> 4) * 8 + j;
        int col = ct * 16 + (lane & 15);
        float v;
        if (mat == 0) {
            int seg = col >> 7, cc = col & 127;
            const float* W = (seg == 0) ? Wq1 : (seg == 1) ? Wk1 : (seg == 2) ? Wv1
                             : (seg == 3) ? Ws1 : Wp1;
            v = W[k * 128 + cc];
        } else if (mat == 1) {
            if (col < 512) {
                int seg = col >> 7, cc = col & 127;
                const float* W = (seg == 0) ? Wq2 : (seg == 1) ? Wk2 : (seg == 2) ? Wv2 : Ws2;
                v = W[k * 128 + cc];
            } else {
                v = Wp2[k * 16 + (col - 512)];
            }
        } else if (mat == 2) {
            v = (col < 128) ? W1[k * 128 + col] : W1[(size_t)(128 + k) * 128 + (col - 128)];
        } else {
            v = (k < 16) ? W1[(size_t)(256 + k) * 128 + col] : 0.f;
        }
        __bf16 h = (__bf16)v;
        __bf16 lo = (__bf16)(v - (float)h);
        blkp[lane * 8 + j] = h;
        blkp[512 + lane * 8 + j] = lo;
    }
}

// ---------------------------------------------------------------------------
// CSR build by dst — count, 3-phase parallel scan, scatter, ea copy
// ---------------------------------------------------------------------------
__global__ void count_kernel(const int* __restrict__ dst, int* __restrict__ counts)
{
    int e = blockIdx.x * blockDim.x + threadIdx.x;
    if (e < NE) atomicAdd(&counts[dst[e]], 1);
}

__global__ void scanA_kernel(const int* __restrict__ counts,
                             int* __restrict__ row_start, int* __restrict__ bsum)
{
    __shared__ int lds[1024];
    int t = threadIdx.x, b = blockIdx.x;
    int i = b * 1024 + t;
    int v = (i < NN) ? counts[i] : 0;
    lds[t] = v;
    __syncthreads();
    for (int off = 1; off < 1024; off <<= 1) {
        int u = (t >= off) ? lds[t - off] : 0;
        __syncthreads();
        lds[t] += u;
        __syncthreads();
    }
    if (i < NN) row_start[i] = lds[t] - v;     // block-local exclusive
    if (t == 1023) bsum[b] = lds[1023];
}

__global__ void scanB_kernel(const int* __restrict__ bsum, int* __restrict__ boff)
{
    int t = threadIdx.x;  // 64 lanes
    int orig = (t < SCAN_B) ? bsum[t] : 0;
    int v = orig;
    #pragma unroll
    for (int off = 1; off < 64; off <<= 1) {
        int u = __shfl_up(v, off, 64);
        if (t >= off) v += u;
    }
    if (t < SCAN_B) boff[t] = v - orig;        // exclusive
}

__global__ void scanC_kernel(int* __restrict__ row_start, const int* __restrict__ boff,
                             int* __restrict__ cursor)
{
    int i = blockIdx.x * 1024 + threadIdx.x;
    if (i < NN) {
        int rs = row_start[i] + boff[blockIdx.x];
        row_start[i] = rs;
        cursor[i] = rs;
    }
    if (i == 0) row_start[NN] = NE;
}

__global__ void scatter_kernel(const int* __restrict__ src, const int* __restrict__ dst,
                               const int* __restrict__ batch,
                               int* __restrict__ cursor, int4* __restrict__ ed4,
                               int* __restrict__ se)
{
    int e = blockIdx.x * blockDim.x + threadIdx.x;
    if (e < NE) {
        int d = dst[e];
        int s = src[e];
        int p = atomicAdd(&cursor[d], 1);
        ed4[p] = make_int4(e, s, d, batch[s]);
        se[p] = s;
    }
}

__global__ void eacopy_kernel(const int4* __restrict__ ed4, const float* __restrict__ ea,
                              float* __restrict__ eac)
{
    int g = blockIdx.x * blockDim.x + threadIdx.x;  // NE*16 threads
    int idx = g >> 4, c = g & 15;
    eac[g] = ea[(size_t)ed4[idx].x * 16 + c];
}

// ---------------------------------------------------------------------------
// MFMA GEMM, split-bf16 3-term. Columns in [CLO,CHI) go to fp16 aux buffer
// (width CHI-CLO); other columns to fp32 out (stride ldo).
// ---------------------------------------------------------------------------
__device__ __forceinline__ void load_split(const float* ap, bool ok,
                                           bf16x8& hv, bf16x8& lv)
{
    float av[8];
    if (ok) {
        float4 f0 = *(const float4*)ap;
        float4 f1 = *(const float4*)(ap + 4);
        av[0] = f0.x; av[1] = f0.y; av[2] = f0.z; av[3] = f0.w;
        av[4] = f1.x; av[5] = f1.y; av[6] = f1.z; av[7] = f1.w;
    } else {
        #pragma unroll
        for (int j = 0; j < 8; ++j) av[j] = 0.f;
    }
    #pragma unroll
    for (int j = 0; j < 8; ++j) {
        __bf16 h = (__bf16)av[j];
        hv[j] = h;
        lv[j] = (__bf16)(av[j] - (float)h);
    }
}

template<int KD, int NCT, bool BIAS, int CLO, int CHI>
__global__ void mfma_gemm_kernel(const float* __restrict__ A, const __bf16* __restrict__ pk,
                                 const float* __restrict__ bias, float* __restrict__ out,
                                 int ldo, _Float16* __restrict__ auxh)
{
    constexpr int NKT = KD / 32;
    constexpr int AUXW = CHI - CLO;
    int t = threadIdx.x, w = t >> 6, l = t & 63;
    int rbase = blockIdx.x * 128 + w * 32;
    int lr = l & 15, kq = l >> 4;
    int r0 = rbase + lr, r1 = rbase + 16 + lr;
    bool ok0 = r0 < NN, ok1 = r1 < NN;
    bf16x8 ah0[NKT], al0[NKT], ah1[NKT], al1[NKT];
    #pragma unroll
    for (int kt = 0; kt < NKT; ++kt) {
        load_split(A + (size_t)r0 * KD + kt * 32 + kq * 8, ok0, ah0[kt], al0[kt]);
        load_split(A + (size_t)r1 * KD + kt * 32 + kq * 8, ok1, ah1[kt], al1[kt]);
    }
    for (int ct = 0; ct < NCT; ++ct) {
        float b = BIAS ? bias[ct * 16 + lr] : 0.f;
        f32x4 acc0 = {b, b, b, b};
        f32x4 acc1 = {b, b, b, b};
        const __bf16* blk = pk + (size_t)ct * 1024;
        #pragma unroll
        for (int kt = 0; kt < NKT; ++kt) {
            bf16x8 bh = *(const bf16x8*)(blk + (size_t)kt * NCT * 1024 + l * 8);
            bf16x8 bl = *(const bf16x8*)(blk + (size_t)kt * NCT * 1024 + 512 + l * 8);
            acc0 = __builtin_amdgcn_mfma_f32_16x16x32_bf16(al0[kt], bh, acc0, 0, 0, 0);
            acc1 = __builtin_amdgcn_mfma_f32_16x16x32_bf16(al1[kt], bh, acc1, 0, 0, 0);
            acc0 = __builtin_amdgcn_mfma_f32_16x16x32_bf16(ah0[kt], bl, acc0, 0, 0, 0);
            acc1 = __builtin_amdgcn_mfma_f32_16x16x32_bf16(ah1[kt], bl, acc1, 0, 0, 0);
            acc0 = __builtin_amdgcn_mfma_f32_16x16x32_bf16(ah0[kt], bh, acc0, 0, 0, 0);
            acc1 = __builtin_amdgcn_mfma_f32_16x16x32_bf16(ah1[kt], bh, acc1, 0, 0, 0);
        }
        int col = ct * 16 + lr;
        bool inAux = (col >= CLO) && (col < CHI);
        #pragma unroll
        for (int i = 0; i < 4; ++i) {
            int ra = rbase + kq * 4 + i;
            int rb = ra + 16;
            if (ra < NN) {
                if (inAux) auxh[(size_t)ra * AUXW + (col - CLO)] = (_Float16)acc0[i];
                else       out[(size_t)ra * ldo + col] = acc0[i];
            }
            if (rb < NN) {
                if (inAux) auxh[(size_t)rb * AUXW + (col - CLO)] = (_Float16)acc1[i];
                else       out[(size_t)rb * ldo + col] = acc1[i];
            }
        }
    }
}

// ---------------------------------------------------------------------------
// eaw: eaWh[E,128] = eac[E,16] @ W1c (split-bf16, K padded to 32). fp16 out.
// Wave = 32 rows; 4 waves/block -> 128 rows/block; NE/128 blocks exactly.
// ---------------------------------------------------------------------------
__global__ void eaw_kernel(const float* __restrict__ eac, const __bf16* __restrict__ pk,
                           _Float16* __restrict__ eaWh)
{
    int t = threadIdx.x, w = t >> 6, l = t & 63;
    int rbase = blockIdx.x * 128 + w * 32;
    int lr = l & 15, kq = l >> 4;
    bf16x8 ah0, al0, ah1, al1;
    if (kq < 2) {
        load_split(eac + (size_t)(rbase + lr) * 16 + kq * 8, true, ah0, al0);
        load_split(eac + (size_t)(rbase + 16 + lr) * 16 + kq * 8, true, ah1, al1);
    } else {
        #pragma unroll
        for (int j = 0; j < 8; ++j) { ah0[j] = (__bf16)0.f; al0[j] = (__bf16)0.f;
                                      ah1[j] = (__bf16)0.f; al1[j] = (__bf16)0.f; }
    }
    #pragma unroll
    for (int ct = 0; ct < 8; ++ct) {
        f32x4 acc0 = {0.f, 0.f, 0.f, 0.f};
        f32x4 acc1 = {0.f, 0.f, 0.f, 0.f};
        const __bf16* blk = pk + (size_t)ct * 1024;
        bf16x8 bh = *(const bf16x8*)(blk + l * 8);
        bf16x8 bl = *(const bf16x8*)(blk + 512 + l * 8);
        acc0 = __builtin_amdgcn_mfma_f32_16x16x32_bf16(al0, bh, acc0, 0, 0, 0);
        acc1 = __builtin_amdgcn_mfma_f32_16x16x32_bf16(al1, bh, acc1, 0, 0, 0);
        acc0 = __builtin_amdgcn_mfma_f32_16x16x32_bf16(ah0, bl, acc0, 0, 0, 0);
        acc1 = __builtin_amdgcn_mfma_f32_16x16x32_bf16(ah1, bl, acc1, 0, 0, 0);
        acc0 = __builtin_amdgcn_mfma_f32_16x16x32_bf16(ah0, bh, acc0, 0, 0, 0);
        acc1 = __builtin_amdgcn_mfma_f32_16x16x32_bf16(ah1, bh, acc1, 0, 0, 0);
        int col = ct * 16 + lr;
        #pragma unroll
        for (int i = 0; i < 4; ++i) {
            int ra = rbase + kq * 4 + i;
            eaWh[(size_t)ra * 128 + col] = (_Float16)acc0[i];
            eaWh[(size_t)(ra + 16) * 128 + col] = (_Float16)acc1[i];
        }
    }
}

// ---------------------------------------------------------------------------
// agg1: wave per node. f32 OUT1 row [Q|-|-|S|P] stride 640; fp16 KVh [K|V] 256.
// lane = h*8 + p; lane owns j = 2p, 2p+1 of head h. 2-way edge unroll.
// ---------------------------------------------------------------------------
__global__ void agg1_kernel(const float* __restrict__ OUT1, const _Float16* __restrict__ KVh,
                            const int* __restrict__ row_start,
                            const int* __restrict__ se, const float* __restrict__ eac,
                            const float* __restrict__ We1, float* __restrict__ h1)
{
    __shared__ float we[16 * 128];
    int t = threadIdx.x;
    for (int i = t; i < 2048; i += 256) we[i] = We1[i];
    __syncthreads();
    int bid = xcd_swz(blockIdx.x, gridDim.x);
    int wv = t >> 6, l = t & 63;
    int n = bid * 4 + wv;
    if (n >= NN) return;
    int h = l >> 3, p = l & 7;
    int j0 = p * 2;
    const float* qb = OUT1 + (size_t)n * 640;
    float2 q = *(const float2*)(qb + h * 16 + j0);
    float2 P = *(const float2*)(qb + 512 + h * 16 + j0);
    float2 accv = make_float2(0.f, 0.f), acce = make_float2(0.f, 0.f);
    float denom = 0.f;
    int e0 = row_start[n], e1 = row_start[n + 1];
    int idx = e0;
    for (; idx + 1 < e1; idx += 2) {
        int sA = se[idx], sB = se[idx + 1];
        const _Float16* kvA = KVh + (size_t)sA * 256;
        const _Float16* kvB = KVh + (size_t)sB * 256;
        h16x2 kAh = *(const h16x2*)(kvA + h * 16 + j0);
        h16x2 vAh = *(const h16x2*)(kvA + 128 + h * 16 + j0);
        float2 eA = *(const float2*)(eac + (size_t)idx * 16 + j0);
        h16x2 kBh = *(const h16x2*)(kvB + h * 16 + j0);
        h16x2 vBh = *(const h16x2*)(kvB + 128 + h * 16 + j0);
        float2 eB = *(const float2*)(eac + (size_t)(idx + 1) * 16 + j0);
        float pa = q.x * (float)kAh[0] + q.y * (float)kAh[1] + P.x * eA.x + P.y * eA.y;
        float pb = q.x * (float)kBh[0] + q.y * (float)kBh[1] + P.x * eB.x + P.y * eB.y;
        pa += __shfl_xor(pa, 1, 64); pb += __shfl_xor(pb, 1, 64);
        pa += __shfl_xor(pa, 2, 64); pb += __shfl_xor(pb, 2, 64);
        pa += __shfl_xor(pa, 4, 64); pb += __shfl_xor(pb, 4, 64);
        float wA = __expf(pa * 0.25f);
        float wB = __expf(pb * 0.25f);
        denom += wA + wB;
        accv.x += wA * (float)vAh[0] + wB * (float)vBh[0];
        accv.y += wA * (float)vAh[1] + wB * (float)vBh[1];
        acce.x += wA * eA.x + wB * eB.x;
        acce.y += wA * eA.y + wB * eB.y;
    }
    if (idx < e1) {
        int s = se[idx];
        const _Float16* kvb = KVh + (size_t)s * 256;
        h16x2 kk = *(const h16x2*)(kvb + h * 16 + j0);
        h16x2 vv = *(const h16x2*)(kvb + 128 + h * 16 + j0);
        float2 ee = *(const float2*)(eac + (size_t)idx * 16 + j0);
        float part = q.x * (float)kk[0] + q.y * (float)kk[1] + P.x * ee.x + P.y * ee.y;
        part += __shfl_xor(part, 1, 64);
        part += __shfl_xor(part, 2, 64);
        part += __shfl_xor(part, 4, 64);
        float w = __expf(part * 0.25f);
        denom += w;
        accv.x += w * (float)vv[0]; accv.y += w * (float)vv[1];
        acce.x += w * ee.x; acce.y += w * ee.y;
    }
    float inv = (denom > 0.f) ? 1.f / denom : 0.f;
    float es0 = 0.f, es1 = 0.f;
    int gbase = h * 8;
    #pragma unroll
    for (int dd = 0; dd < 8; ++dd) {
        float a0 = __shfl(acce.x, gbase + dd, 64);
        float a1 = __shfl(acce.y, gbase + dd, 64);
        es0 += a0 * we[(2 * dd) * 128 + h * 16 + j0]     + a1 * we[(2 * dd + 1) * 128 + h * 16 + j0];
        es1 += a0 * we[(2 * dd) * 128 + h * 16 + j0 + 1] + a1 * we[(2 * dd + 1) * 128 + h * 16 + j0 + 1];
    }
    float2 sk = *(const float2*)(qb + 384 + h * 16 + j0);
    float o0 = (accv.x + es0) * inv + sk.x;
    float o1 = (accv.y + es1) * inv + sk.y;
    o0 = (o0 > 0.f) ? o0 : 0.01f * o0;
    o1 = (o1 > 0.f) ? o1 : 0.01f * o1;
    *(float2*)(h1 + (size_t)n * 128 + h * 16 + j0) = make_float2(o0, o1);
}

// ---------------------------------------------------------------------------
// agg2: wave per node, half-wave per edge. f32 OUT2 [Q|-|-|S|P2] stride 528;
// fp16 KVh [K|V] 256. lane = half*32 + c; lane owns dims {c,c+32,c+64,c+96}.
// ---------------------------------------------------------------------------
__global__ void agg2_kernel(const float* __restrict__ OUT2, const _Float16* __restrict__ KVh,
                            const int* __restrict__ row_start,
                            const int* __restrict__ se, const float* __restrict__ eac,
                            const float* __restrict__ We2, float* __restrict__ h2)
{
    int bid = xcd_swz(blockIdx.x, gridDim.x);
    int t = threadIdx.x;
    int wv = t >> 6, l = t & 63;
    int n = bid * 4 + wv;
    if (n >= NN) return;
    int half = l >> 5, c = l & 31;
    const float* base = OUT2 + (size_t)n * 528;
    float q0 = base[c], q1 = base[32 + c], q2 = base[64 + c], q3 = base[96 + c];
    float p2 = (c < 16) ? base[512 + c] : 0.f;
    float av0 = 0.f, av1 = 0.f, av2 = 0.f, av3 = 0.f, ae = 0.f, denom = 0.f;
    int e0 = row_start[n], e1 = row_start[n + 1];
    for (int idx = e0 + half; idx < e1; idx += 2) {
        int s = se[idx];
        const _Float16* kb = KVh + (size_t)s * 256;
        float k0 = (float)kb[c], k1 = (float)kb[32 + c];
        float k2 = (float)kb[64 + c], k3 = (float)kb[96 + c];
        float v0 = (float)kb[128 + c], v1 = (float)kb[160 + c];
        float v2 = (float)kb[192 + c], v3 = (float)kb[224 + c];
        float eav = (c < 16) ? eac[(size_t)idx * 16 + c] : 0.f;
        float part = q0 * k0 + q1 * k1 + q2 * k2 + q3 * k3 + p2 * eav;
        part += __shfl_xor(part, 1, 64);
        part += __shfl_xor(part, 2, 64);
        part += __shfl_xor(part, 4, 64);
        part += __shfl_xor(part, 8, 64);
        part += __shfl_xor(part, 16, 64);
        float w = __expf(part * 0.08838834764831845f);  // 1/sqrt(128)
        denom += w;
        av0 += w * v0; av1 += w * v1; av2 += w * v2; av3 += w * v3;
        ae += w * eav;
    }
    denom += __shfl_xor(denom, 32, 64);
    av0 += __shfl_xor(av0, 32, 64);
    av1 += __shfl_xor(av1, 32, 64);
    av2 += __shfl_xor(av2, 32, 64);
    av3 += __shfl_xor(av3, 32, 64);
    ae  += __shfl_xor(ae, 32, 64);
    float inv = (denom > 0.f) ? 1.f / denom : 0.f;
    float t0 = 0.f, t1 = 0.f, t2 = 0.f, t3 = 0.f;
    #pragma unroll
    for (int d = 0; d < 16; ++d) {
        float aed = __shfl(ae, d, 64);
        t0 += aed * We2[d * 128 + c];
        t1 += aed * We2[d * 128 + 32 + c];
        t2 += aed * We2[d * 128 + 64 + c];
        t3 += aed * We2[d * 128 + 96 + c];
    }
    if (half == 0) {
        float* hp = h2 + (size_t)n * 128;
        hp[c]      = (av0 + t0) * inv + base[384 + c];
        hp[32 + c] = (av1 + t1) * inv + base[416 + c];
        hp[64 + c] = (av2 + t2) * inv + base[448 + c];
        hp[96 + c] = (av3 + t3) * inv + base[480 + c];
    }
}

// ---------------------------------------------------------------------------
// pooling: sorted batch -> register-accumulated flushes
// ---------------------------------------------------------------------------
__global__ void pool_kernel(const float* __restrict__ h2, const int* __restrict__ batch,
                            float* __restrict__ sums, float* __restrict__ cnt)
{
    int t = threadIdx.x;
    int c = t & 127, half = t >> 7;
    int n0 = blockIdx.x * 64;
    float acc = 0.f, cacc = 0.f;
    int curg = -1;
    for (int r = half; r < 64; r += 2) {
        int n = n0 + r;
        if (n >= NN) break;
        int g = batch[n];
        if (g != curg) {
            if (curg >= 0) {
                atomicAdd(&sums[curg * 128 + c], acc);
                if (c == 0) atomicAdd(&cnt[curg], cacc);
            }
            curg = g; acc = 0.f; cacc = 0.f;
        }
        acc += h2[(size_t)n * 128 + c];
        cacc += 1.f;
    }
    if (curg >= 0) {
        atomicAdd(&sums[curg * 128 + c], acc);
        if (c == 0) atomicAdd(&cnt[curg], cacc);
    }
}

// Gp[g,c] = b1[c] + sum_m pool[g,m] * W1[272+m, c]
__global__ void gp_kernel(const float* __restrict__ sums, const float* __restrict__ cnt,
                          const float* __restrict__ W1, const float* __restrict__ b1,
                          float* __restrict__ Gp)
{
    __shared__ float pr[128];
    int g = blockIdx.x, c = threadIdx.x;
    float inv = 1.f / fmaxf(cnt[g], 1.f);
    pr[c] = sums[g * 128 + c] * inv;
    __syncthreads();
    float acc = b1[c];
    for (int m = 0; m < 128; ++m) acc += pr[m] * W1[(272 + m) * 128 + c];
    Gp[g * 128 + c] = acc;
}

// ---------------------------------------------------------------------------
// final: half-wave per CSR slot; lane owns 4 CONTIGUOUS cols [4c,4c+4).
// hid = A[s] + B[d] + Gp[g] + eaW[idx]; relu; dot W2. Pure gather+add.
// ---------------------------------------------------------------------------
__global__ void edge_out_kernel(const _Float16* __restrict__ ABh, const float* __restrict__ Gp,
                                const int4* __restrict__ ed4, const _Float16* __restrict__ eaWh,
                                const float* __restrict__ W2, const float* __restrict__ b2,
                                float* __restrict__ out)
{
    int t = threadIdx.x;
    int wv = t >> 6, l = t & 63;
    int half = l >> 5, c = l & 31;
    float4 w2r = *(const float4*)(W2 + 4 * c);
    float bias2 = b2[0];
    int bid = xcd_swz(blockIdx.x, gridDim.x);
    int base = bid * 128 + wv * 32;            // NE == gridDim*128 exactly
    for (int it = 0; it < 16; ++it) {
        int idx = base + it * 2 + half;
        int4 q4 = ed4[idx];
        int e = q4.x, s = q4.y, d = q4.z, g = q4.w;
        h16x4 As = *(const h16x4*)(ABh + (size_t)s * 256 + 4 * c);
        h16x4 Bd = *(const h16x4*)(ABh + (size_t)d * 256 + 128 + 4 * c);
        h16x4 ew = *(const h16x4*)(eaWh + (size_t)idx * 128 + 4 * c);
        float4 Gg = *(const float4*)(Gp + g * 128 + 4 * c);
        float h0 = fmaxf((float)As[0] + (float)Bd[0] + Gg.x + (float)ew[0], 0.f);
        float h1 = fmaxf((float)As[1] + (float)Bd[1] + Gg.y + (float)ew[1], 0.f);
        float h2 = fmaxf((float)As[2] + (float)Bd[2] + Gg.z + (float)ew[2], 0.f);
        float h3 = fmaxf((float)As[3] + (float)Bd[3] + Gg.w + (float)ew[3], 0.f);
        float r = h0 * w2r.x + h1 * w2r.y + h2 * w2r.z + h3 * w2r.w;
        r += __shfl_xor(r, 1, 64);
        r += __shfl_xor(r, 2, 64);
        r += __shfl_xor(r, 4, 64);
        r += __shfl_xor(r, 8, 64);
        r += __shfl_xor(r, 16, 64);
        if (c == 0) out[e] = r + bias2;
    }
}

// ---------------------------------------------------------------------------
extern "C" void kernel_launch(void* const* d_in, const int* in_sizes, int n_in,
                              void* d_out, int out_size, void* d_ws, size_t ws_size,
                              hipStream_t stream)
{
    const float* x   = (const float*)d_in[0];
    const int* ei    = (const int*)d_in[1];
    const float* ea  = (const float*)d_in[2];
    const int* batch = (const int*)d_in[3];
    const float* Wq1 = (const float*)d_in[4];  const float* bq1 = (const float*)d_in[5];
    const float* Wk1 = (const float*)d_in[6];  const float* bk1 = (const float*)d_in[7];
    const float* Wv1 = (const float*)d_in[8];  const float* bv1 = (const float*)d_in[9];
    const float* We1 = (const float*)d_in[10];
    const float* Ws1 = (const float*)d_in[11]; const float* bs1 = (const float*)d_in[12];
    const float* Wq2 = (const float*)d_in[13]; const float* bq2 = (const float*)d_in[14];
    const float* Wk2 = (const float*)d_in[15]; const float* bk2 = (const float*)d_in[16];
    const float* Wv2 = (const float*)d_in[17]; const float* bv2 = (const float*)d_in[18];
    const float* We2 = (const float*)d_in[19];
    const float* Ws2 = (const float*)d_in[20]; const float* bs2 = (const float*)d_in[21];
    const float* W1  = (const float*)d_in[22]; const float* b1  = (const float*)d_in[23];
    const float* W2  = (const float*)d_in[24]; const float* b2  = (const float*)d_in[25];

    const int* src = ei;
    const int* dst = ei + NE;

    float* ws = (float*)d_ws;
    size_t off = 0;
    float* OUT  = ws + off; off += (size_t)NN * 640;  // OUT1/OUT2; later ABh + eaWh (exact fit)
    float* h1   = ws + off; off += (size_t)NN * 128;
    float* h2   = ws + off; off += (size_t)NN * 128;
    float* eac  = ws + off; off += (size_t)NE * 16;
    _Float16* KVh = (_Float16*)(ws + off); off += (size_t)NN * 128;  // N x 256 half
    float* sums = ws + off; off += NG * 128;
    float* cntf = ws + off; off += NG;
    float* Gp   = ws + off; off += NG * 128;
    float* Wp1  = ws + off; off += 64 * 128;
    float* Wp2  = ws + off; off += 128 * 16;
    float* bcat1 = ws + off; off += 640;
    float* bcat2 = ws + off; off += 528;
    __bf16* pk  = (__bf16*)(ws + off); off += 284 * 1024 / 2;  // 284 blocks x 1024 bf16
    int* cnt_arr   = (int*)(ws + off); off += NN;
    int* row_start = (int*)(ws + off); off += NN + 1;
    int* cursor    = (int*)(ws + off); off += NN;
    int* se        = (int*)(ws + off); off += NE;
    int* bsum      = (int*)(ws + off); off += 64;
    int* boff      = (int*)(ws + off); off += 64;
    off = (off + 3) & ~(size_t)3;                      // 16B align for int4
    int4* ed4      = (int4*)(ws + off); off += (size_t)NE * 4;
    // alias: after agg2, OUT region = ABh (NN*256 half) ++ eaWh (NE*128 half) = NN*640 floats
    _Float16* ABh  = (_Float16*)OUT;
    _Float16* eaWh = (_Float16*)(OUT + (size_t)NN * 128);

    hipMemsetAsync(cnt_arr, 0, NN * sizeof(int), stream);
    hipMemsetAsync(sums, 0, (NG * 128 + NG) * sizeof(float), stream);

    prep_kernel<<<45, 256, 0, stream>>>(Wq1, bq1, bk1, bv1, bs1, We1,
                                        Wq2, bq2, bk2, bv2, bs2, We2,
                                        Wp1, Wp2, bcat1, bcat2);
    pack_kernel<<<284, 256, 0, stream>>>(Wq1, Wk1, Wv1, Ws1, Wp1,
                                         Wq2, Wk2, Wv2, Ws2, Wp2, W1, pk);
    count_kernel<<<(NE + 255) / 256, 256, 0, stream>>>(dst, cnt_arr);
    scanA_kernel<<<SCAN_B, 1024, 0, stream>>>(cnt_arr, row_start, bsum);
    scanB_kernel<<<1, 64, 0, stream>>>(bsum, boff);
    scanC_kernel<<<SCAN_B, 1024, 0, stream>>>(row_start, boff, cursor);
    scatter_kernel<<<(NE + 255) / 256, 256, 0, stream>>>(src, dst, batch, cursor, ed4, se);
    eacopy_kernel<<<NE * 16 / 256, 256, 0, stream>>>(ed4, ea, eac);

    mfma_gemm_kernel<64, 40, true, 128, 384><<<(NN + 127) / 128, 256, 0, stream>>>(
        x, pk, bcat1, OUT, 640, KVh);
    agg1_kernel<<<(NN + 3) / 4, 256, 0, stream>>>(OUT, KVh, row_start, se, eac, We1, h1);
    mfma_gemm_kernel<128, 33, true, 128, 384><<<(NN + 127) / 128, 256, 0, stream>>>(
        h1, pk + (size_t)80 * 1024, bcat2, OUT, 528, KVh);
    agg2_kernel<<<(NN + 3) / 4, 256, 0, stream>>>(OUT, KVh, row_start, se, eac, We2, h2);
    pool_kernel<<<(NN + 63) / 64, 256, 0, stream>>>(h2, batch, sums, cntf);
    gp_kernel<<<NG, 128, 0, stream>>>(sums, cntf, W1, b1, Gp);
    mfma_gemm_kernel<128, 16, false, 0, 256><<<(NN + 127) / 128, 256, 0, stream>>>(
        h2, pk + (size_t)212 * 1024, nullptr, nullptr, 0, ABh);
    eaw_kernel<<<NE / 128, 256, 0, stream>>>(eac, pk + (size_t)276 * 1024, eaWh);
    edge_out_kernel<<<NE / 128, 256, 0, stream>>>(ABh, Gp, ed4, eaWh,
                                                  W2, b2, (float*)d_out);
}

// Round 9
// 434.353 us; speedup vs baseline: 1.0510x; 1.0510x over previous
//
#include <hip/hip_runtime.h>
#include <math.h>

#define NN 50000
#define NE 400000
#define NG 128
#define SCAN_B 49   // ceil(NN/1024)

typedef __bf16 bf16x8 __attribute__((ext_vector_type(8)));
typedef float f32x4 __attribute__((ext_vector_type(4)));
typedef _Float16 h16x2 __attribute__((ext_vector_type(2)));
typedef _Float16 h16x4 __attribute__((ext_vector_type(4)));

// bijective XCD-chunked swizzle (m204): each XCD gets a contiguous chunk
__device__ __forceinline__ int xcd_swz(int bid, int nwg)
{
    int q = nwg >> 3, r = nwg & 7;
    int xcd = bid & 7, off = bid >> 3;
    return (xcd < r ? xcd * (q + 1) : r * (q + 1) + (xcd - r) * q) + off;
}

// ---------------------------------------------------------------------------
// prep: fused weights Wp1[64,128], Wp2[128,16]; concatenated biases
// ---------------------------------------------------------------------------
__global__ void prep_kernel(const float* __restrict__ Wq1, const float* __restrict__ bq1,
                            const float* __restrict__ bk1, const float* __restrict__ bv1,
                            const float* __restrict__ bs1, const float* __restrict__ We1,
                            const float* __restrict__ Wq2, const float* __restrict__ bq2,
                            const float* __restrict__ bk2, const float* __restrict__ bv2,
                            const float* __restrict__ bs2, const float* __restrict__ We2,
                            float* __restrict__ Wp1, float* __restrict__ Wp2,
                            float* __restrict__ bcat1, float* __restrict__ bcat2)
{
    int idx = blockIdx.x * blockDim.x + threadIdx.x;
    if (idx < 8192) {                       // Wp1[64,128]
        int m = idx >> 7, c = idx & 127;
        int h = c >> 4, d = c & 15;
        float s = 0.f;
        #pragma unroll
        for (int j = 0; j < 16; ++j)
            s += Wq1[m * 128 + h * 16 + j] * We1[d * 128 + h * 16 + j];
        Wp1[idx] = s;
    } else if (idx < 8320) {                // bp1 -> bcat1[512..640)
        int c = idx - 8192;
        int h = c >> 4, d = c & 15;
        float s = 0.f;
        #pragma unroll
        for (int j = 0; j < 16; ++j)
            s += bq1[h * 16 + j] * We1[d * 128 + h * 16 + j];
        bcat1[512 + c] = s;
    } else if (idx < 10368) {               // Wp2[128,16]
        int i = idx - 8320;
        int m = i >> 4, d = i & 15;
        float s = 0.f;
        for (int j = 0; j < 128; ++j)
            s += Wq2[m * 128 + j] * We2[d * 128 + j];
        Wp2[m * 16 + d] = s;
    } else if (idx < 10384) {               // bp2 -> bcat2[512..528)
        int d = idx - 10368;
        float s = 0.f;
        for (int j = 0; j < 128; ++j)
            s += bq2[j] * We2[d * 128 + j];
        bcat2[512 + d] = s;
    } else if (idx < 10896) {               // bcat1[0..512)
        int i = idx - 10384;
        int seg = i >> 7, c = i & 127;
        const float* b = (seg == 0) ? bq1 : (seg == 1) ? bk1 : (seg == 2) ? bv1 : bs1;
        bcat1[i] = b[c];
    } else if (idx < 11408) {               // bcat2[0..512)
        int i = idx - 10896;
        int seg = i >> 7, c = i & 127;
        const float* b = (seg == 0) ? bq2 : (seg == 1) ? bk2 : (seg == 2) ? bv2 : bs2;
        bcat2[i] = b[c];
    }
}

// ---------------------------------------------------------------------------
// pack: MFMA fragment-ready hi/lo bf16 weight blocks.
//   mat0: gemm1 Wcat[64,640]   blocks 0..79
//   mat1: gemm2 Wcat[128,528]  blocks 80..211
//   mat2: gemm3 Wcat[128,256]  blocks 212..275
//   mat3: W1c[16->32pad,128]   blocks 276..283 (for eaW GEMM)
// ---------------------------------------------------------------------------
__global__ void pack_kernel(const float* __restrict__ Wq1, const float* __restrict__ Wk1,
                            const float* __restrict__ Wv1, const float* __restrict__ Ws1,
                            const float* __restrict__ Wp1,
                            const float* __restrict__ Wq2, const float* __restrict__ Wk2,
                            const float* __restrict__ Wv2, const float* __restrict__ Ws2,
                            const float* __restrict__ Wp2,
                            const float* __restrict__ W1,
                            __bf16* __restrict__ pk)
{
    int b = blockIdx.x;
    int mat, kt, ct;
    if (b < 80)       { mat = 0; kt = b / 40;        ct = b % 40; }
    else if (b < 212) { mat = 1; kt = (b - 80) / 33; ct = (b - 80) % 33; }
    else if (b < 276) { mat = 2; kt = (b - 212) / 16; ct = (b - 212) % 16; }
    else              { mat = 3; kt = 0;             ct = b - 276; }
    __bf16* blkp = pk + (size_t)b * 1024;
    for (int item = threadIdx.x; item < 512; item += 256) {
        int lane = item >> 3, j = item & 7;
        int k = kt * 32 + (lane >> 4) * 8 + j;
        int col = ct * 16 + (lane & 15);
        float v;
        if (mat == 0) {
            int seg = col >> 7, cc = col & 127;
            const float* W = (seg == 0) ? Wq1 : (seg == 1) ? Wk1 : (seg == 2) ? Wv1
                             : (seg == 3) ? Ws1 : Wp1;
            v = W[k * 128 + cc];
        } else if (mat == 1) {
            if (col < 512) {
                int seg = col >> 7, cc = col & 127;
                const float* W = (seg == 0) ? Wq2 : (seg == 1) ? Wk2 : (seg == 2) ? Wv2 : Ws2;
                v = W[k * 128 + cc];
            } else {
                v = Wp2[k * 16 + (col - 512)];
            }
        } else if (mat == 2) {
            v = (col < 128) ? W1[k * 128 + col] : W1[(size_t)(128 + k) * 128 + (col - 128)];
        } else {
            v = (k < 16) ? W1[(size_t)(256 + k) * 128 + col] : 0.f;
        }
        __bf16 h = (__bf16)v;
        __bf16 lo = (__bf16)(v - (float)h);
        blkp[lane * 8 + j] = h;
        blkp[512 + lane * 8 + j] = lo;
    }
}

// ---------------------------------------------------------------------------
// CSR build by dst — count, 3-phase parallel scan, scatter, ea copy
// ---------------------------------------------------------------------------
__global__ void count_kernel(const int* __restrict__ dst, int* __restrict__ counts)
{
    int e = blockIdx.x * blockDim.x + threadIdx.x;
    if (e < NE) atomicAdd(&counts[dst[e]], 1);
}

__global__ void scanA_kernel(const int* __restrict__ counts,
                             int* __restrict__ row_start, int* __restrict__ bsum)
{
    __shared__ int lds[1024];
    int t = threadIdx.x, b = blockIdx.x;
    int i = b * 1024 + t;
    int v = (i < NN) ? counts[i] : 0;
    lds[t] = v;
    __syncthreads();
    for (int off = 1; off < 1024; off <<= 1) {
        int u = (t >= off) ? lds[t - off] : 0;
        __syncthreads();
        lds[t] += u;
        __syncthreads();
    }
    if (i < NN) row_start[i] = lds[t] - v;     // block-local exclusive
    if (t == 1023) bsum[b] = lds[1023];
}

__global__ void scanB_kernel(const int* __restrict__ bsum, int* __restrict__ boff)
{
    int t = threadIdx.x;  // 64 lanes
    int orig = (t < SCAN_B) ? bsum[t] : 0;
    int v = orig;
    #pragma unroll
    for (int off = 1; off < 64; off <<= 1) {
        int u = __shfl_up(v, off, 64);
        if (t >= off) v += u;
    }
    if (t < SCAN_B) boff[t] = v - orig;        // exclusive
}

__global__ void scanC_kernel(int* __restrict__ row_start, const int* __restrict__ boff,
                             int* __restrict__ cursor)
{
    int i = blockIdx.x * 1024 + threadIdx.x;
    if (i < NN) {
        int rs = row_start[i] + boff[blockIdx.x];
        row_start[i] = rs;
        cursor[i] = rs;
    }
    if (i == 0) row_start[NN] = NE;
}

__global__ void scatter_kernel(const int* __restrict__ src, const int* __restrict__ dst,
                               const int* __restrict__ batch,
                               int* __restrict__ cursor, int4* __restrict__ ed4,
                               int* __restrict__ se)
{
    int e = blockIdx.x * blockDim.x + threadIdx.x;
    if (e < NE) {
        int d = dst[e];
        int s = src[e];
        int p = atomicAdd(&cursor[d], 1);
        ed4[p] = make_int4(e, s, d, batch[s]);
        se[p] = s;
    }
}

__global__ void eacopy_kernel(const int4* __restrict__ ed4, const float* __restrict__ ea,
                              float* __restrict__ eac)
{
    int g = blockIdx.x * blockDim.x + threadIdx.x;  // NE*16 threads
    int idx = g >> 4, c = g & 15;
    eac[g] = ea[(size_t)ed4[idx].x * 16 + c];
}

// ---------------------------------------------------------------------------
// MFMA GEMM, split-bf16 3-term. Columns in [CLO,CHI) go to fp16 aux buffer
// (width CHI-CLO); other columns to fp32 out (stride ldo).
// Column tiles split across blockIdx.y (NCG groups) for occupancy.
// ---------------------------------------------------------------------------
__device__ __forceinline__ void load_split(const float* ap, bool ok,
                                           bf16x8& hv, bf16x8& lv)
{
    float av[8];
    if (ok) {
        float4 f0 = *(const float4*)ap;
        float4 f1 = *(const float4*)(ap + 4);
        av[0] = f0.x; av[1] = f0.y; av[2] = f0.z; av[3] = f0.w;
        av[4] = f1.x; av[5] = f1.y; av[6] = f1.z; av[7] = f1.w;
    } else {
        #pragma unroll
        for (int j = 0; j < 8; ++j) av[j] = 0.f;
    }
    #pragma unroll
    for (int j = 0; j < 8; ++j) {
        __bf16 h = (__bf16)av[j];
        hv[j] = h;
        lv[j] = (__bf16)(av[j] - (float)h);
    }
}

template<int KD, int NCT, int NCG, bool BIAS, int CLO, int CHI>
__global__ void mfma_gemm_kernel(const float* __restrict__ A, const __bf16* __restrict__ pk,
                                 const float* __restrict__ bias, float* __restrict__ out,
                                 int ldo, _Float16* __restrict__ auxh)
{
    constexpr int NKT = KD / 32;
    constexpr int AUXW = CHI - CLO;
    constexpr int CPG = (NCT + NCG - 1) / NCG;
    int cg = blockIdx.y;
    int ct0 = cg * CPG;
    int ct1 = (ct0 + CPG < NCT) ? ct0 + CPG : NCT;
    int t = threadIdx.x, w = t >> 6, l = t & 63;
    int rbase = blockIdx.x * 128 + w * 32;
    int lr = l & 15, kq = l >> 4;
    int r0 = rbase + lr, r1 = rbase + 16 + lr;
    bool ok0 = r0 < NN, ok1 = r1 < NN;
    bf16x8 ah0[NKT], al0[NKT], ah1[NKT], al1[NKT];
    #pragma unroll
    for (int kt = 0; kt < NKT; ++kt) {
        load_split(A + (size_t)r0 * KD + kt * 32 + kq * 8, ok0, ah0[kt], al0[kt]);
        load_split(A + (size_t)r1 * KD + kt * 32 + kq * 8, ok1, ah1[kt], al1[kt]);
    }
    for (int ct = ct0; ct < ct1; ++ct) {
        float b = BIAS ? bias[ct * 16 + lr] : 0.f;
        f32x4 acc0 = {b, b, b, b};
        f32x4 acc1 = {b, b, b, b};
        const __bf16* blk = pk + (size_t)ct * 1024;
        #pragma unroll
        for (int kt = 0; kt < NKT; ++kt) {
            bf16x8 bh = *(const bf16x8*)(blk + (size_t)kt * NCT * 1024 + l * 8);
            bf16x8 bl = *(const bf16x8*)(blk + (size_t)kt * NCT * 1024 + 512 + l * 8);
            acc0 = __builtin_amdgcn_mfma_f32_16x16x32_bf16(al0[kt], bh, acc0, 0, 0, 0);
            acc1 = __builtin_amdgcn_mfma_f32_16x16x32_bf16(al1[kt], bh, acc1, 0, 0, 0);
            acc0 = __builtin_amdgcn_mfma_f32_16x16x32_bf16(ah0[kt], bl, acc0, 0, 0, 0);
            acc1 = __builtin_amdgcn_mfma_f32_16x16x32_bf16(ah1[kt], bl, acc1, 0, 0, 0);
            acc0 = __builtin_amdgcn_mfma_f32_16x16x32_bf16(ah0[kt], bh, acc0, 0, 0, 0);
            acc1 = __builtin_amdgcn_mfma_f32_16x16x32_bf16(ah1[kt], bh, acc1, 0, 0, 0);
        }
        int col = ct * 16 + lr;
        bool inAux = (col >= CLO) && (col < CHI);
        #pragma unroll
        for (int i = 0; i < 4; ++i) {
            int ra = rbase + kq * 4 + i;
            int rb = ra + 16;
            if (ra < NN) {
                if (inAux) auxh[(size_t)ra * AUXW + (col - CLO)] = (_Float16)acc0[i];
                else       out[(size_t)ra * ldo + col] = acc0[i];
            }
            if (rb < NN) {
                if (inAux) auxh[(size_t)rb * AUXW + (col - CLO)] = (_Float16)acc1[i];
                else       out[(size_t)rb * ldo + col] = acc1[i];
            }
        }
    }
}

// ---------------------------------------------------------------------------
// eaw: eaWh[E,128] = eac[E,16] @ W1c (split-bf16, K padded to 32). fp16 out.
// Wave = 32 rows; 4 waves/block -> 128 rows/block; NE/128 blocks exactly.
// ---------------------------------------------------------------------------
__global__ void eaw_kernel(const float* __restrict__ eac, const __bf16* __restrict__ pk,
                           _Float16* __restrict__ eaWh)
{
    int t = threadIdx.x, w = t >> 6, l = t & 63;
    int rbase = blockIdx.x * 128 + w * 32;
    int lr = l & 15, kq = l >> 4;
    bf16x8 ah0, al0, ah1, al1;
    if (kq < 2) {
        load_split(eac + (size_t)(rbase + lr) * 16 + kq * 8, true, ah0, al0);
        load_split(eac + (size_t)(rbase + 16 + lr) * 16 + kq * 8, true, ah1, al1);
    } else {
        #pragma unroll
        for (int j = 0; j < 8; ++j) { ah0[j] = (__bf16)0.f; al0[j] = (__bf16)0.f;
                                      ah1[j] = (__bf16)0.f; al1[j] = (__bf16)0.f; }
    }
    #pragma unroll
    for (int ct = 0; ct < 8; ++ct) {
        f32x4 acc0 = {0.f, 0.f, 0.f, 0.f};
        f32x4 acc1 = {0.f, 0.f, 0.f, 0.f};
        const __bf16* blk = pk + (size_t)ct * 1024;
        bf16x8 bh = *(const bf16x8*)(blk + l * 8);
        bf16x8 bl = *(const bf16x8*)(blk + 512 + l * 8);
        acc0 = __builtin_amdgcn_mfma_f32_16x16x32_bf16(al0, bh, acc0, 0, 0, 0);
        acc1 = __builtin_amdgcn_mfma_f32_16x16x32_bf16(al1, bh, acc1, 0, 0, 0);
        acc0 = __builtin_amdgcn_mfma_f32_16x16x32_bf16(ah0, bl, acc0, 0, 0, 0);
        acc1 = __builtin_amdgcn_mfma_f32_16x16x32_bf16(ah1, bl, acc1, 0, 0, 0);
        acc0 = __builtin_amdgcn_mfma_f32_16x16x32_bf16(ah0, bh, acc0, 0, 0, 0);
        acc1 = __builtin_amdgcn_mfma_f32_16x16x32_bf16(ah1, bh, acc1, 0, 0, 0);
        int col = ct * 16 + lr;
        #pragma unroll
        for (int i = 0; i < 4; ++i) {
            int ra = rbase + kq * 4 + i;
            eaWh[(size_t)ra * 128 + col] = (_Float16)acc0[i];
            eaWh[(size_t)(ra + 16) * 128 + col] = (_Float16)acc1[i];
        }
    }
}

// ---------------------------------------------------------------------------
// agg1: wave per node. f32 OUT1 row [Q|-|-|S|P] stride 640; fp16 KVh [K|V] 256.
// lane = h*8 + p; lane owns j = 2p, 2p+1 of head h. 2-way edge unroll.
// ---------------------------------------------------------------------------
__global__ void agg1_kernel(const float* __restrict__ OUT1, const _Float16* __restrict__ KVh,
                            const int* __restrict__ row_start,
                            const int* __restrict__ se, const float* __restrict__ eac,
                            const float* __restrict__ We1, float* __restrict__ h1)
{
    __shared__ float we[16 * 128];
    int t = threadIdx.x;
    for (int i = t; i < 2048; i += 256) we[i] = We1[i];
    __syncthreads();
    int bid = xcd_swz(blockIdx.x, gridDim.x);
    int wv = t >> 6, l = t & 63;
    int n = bid * 4 + wv;
    if (n >= NN) return;
    int h = l >> 3, p = l & 7;
    int j0 = p * 2;
    const float* qb = OUT1 + (size_t)n * 640;
    float2 q = *(const float2*)(qb + h * 16 + j0);
    float2 P = *(const float2*)(qb + 512 + h * 16 + j0);
    float2 accv = make_float2(0.f, 0.f), acce = make_float2(0.f, 0.f);
    float denom = 0.f;
    int e0 = row_start[n], e1 = row_start[n + 1];
    int idx = e0;
    for (; idx + 1 < e1; idx += 2) {
        int sA = se[idx], sB = se[idx + 1];
        const _Float16* kvA = KVh + (size_t)sA * 256;
        const _Float16* kvB = KVh + (size_t)sB * 256;
        h16x2 kAh = *(const h16x2*)(kvA + h * 16 + j0);
        h16x2 vAh = *(const h16x2*)(kvA + 128 + h * 16 + j0);
        float2 eA = *(const float2*)(eac + (size_t)idx * 16 + j0);
        h16x2 kBh = *(const h16x2*)(kvB + h * 16 + j0);
        h16x2 vBh = *(const h16x2*)(kvB + 128 + h * 16 + j0);
        float2 eB = *(const float2*)(eac + (size_t)(idx + 1) * 16 + j0);
        float pa = q.x * (float)kAh[0] + q.y * (float)kAh[1] + P.x * eA.x + P.y * eA.y;
        float pb = q.x * (float)kBh[0] + q.y * (float)kBh[1] + P.x * eB.x + P.y * eB.y;
        pa += __shfl_xor(pa, 1, 64); pb += __shfl_xor(pb, 1, 64);
        pa += __shfl_xor(pa, 2, 64); pb += __shfl_xor(pb, 2, 64);
        pa += __shfl_xor(pa, 4, 64); pb += __shfl_xor(pb, 4, 64);
        float wA = __expf(pa * 0.25f);
        float wB = __expf(pb * 0.25f);
        denom += wA + wB;
        accv.x += wA * (float)vAh[0] + wB * (float)vBh[0];
        accv.y += wA * (float)vAh[1] + wB * (float)vBh[1];
        acce.x += wA * eA.x + wB * eB.x;
        acce.y += wA * eA.y + wB * eB.y;
    }
    if (idx < e1) {
        int s = se[idx];
        const _Float16* kvb = KVh + (size_t)s * 256;
        h16x2 kk = *(const h16x2*)(kvb + h * 16 + j0);
        h16x2 vv = *(const h16x2*)(kvb + 128 + h * 16 + j0);
        float2 ee = *(const float2*)(eac + (size_t)idx * 16 + j0);
        float part = q.x * (float)kk[0] + q.y * (float)kk[1] + P.x * ee.x + P.y * ee.y;
        part += __shfl_xor(part, 1, 64);
        part += __shfl_xor(part, 2, 64);
        part += __shfl_xor(part, 4, 64);
        float w = __expf(part * 0.25f);
        denom += w;
        accv.x += w * (float)vv[0]; accv.y += w * (float)vv[1];
        acce.x += w * ee.x; acce.y += w * ee.y;
    }
    float inv = (denom > 0.f) ? 1.f / denom : 0.f;
    float es0 = 0.f, es1 = 0.f;
    int gbase = h * 8;
    #pragma unroll
    for (int dd = 0; dd < 8; ++dd) {
        float a0 = __shfl(acce.x, gbase + dd, 64);
        float a1 = __shfl(acce.y, gbase + dd, 64);
        es0 += a0 * we[(2 * dd) * 128 + h * 16 + j0]     + a1 * we[(2 * dd + 1) * 128 + h * 16 + j0];
        es1 += a0 * we[(2 * dd) * 128 + h * 16 + j0 + 1] + a1 * we[(2 * dd + 1) * 128 + h * 16 + j0 + 1];
    }
    float2 sk = *(const float2*)(qb + 384 + h * 16 + j0);
    float o0 = (accv.x + es0) * inv + sk.x;
    float o1 = (accv.y + es1) * inv + sk.y;
    o0 = (o0 > 0.f) ? o0 : 0.01f * o0;
    o1 = (o1 > 0.f) ? o1 : 0.01f * o1;
    *(float2*)(h1 + (size_t)n * 128 + h * 16 + j0) = make_float2(o0, o1);
}

// ---------------------------------------------------------------------------
// agg2: wave per node, half-wave per edge. f32 OUT2 [Q|-|-|S|P2] stride 528;
// fp16 KVh [K|V] 256. lane = half*32 + c; lane owns dims {c,c+32,c+64,c+96}.
// ---------------------------------------------------------------------------
__global__ void agg2_kernel(const float* __restrict__ OUT2, const _Float16* __restrict__ KVh,
                            const int* __restrict__ row_start,
                            const int* __restrict__ se, const float* __restrict__ eac,
                            const float* __restrict__ We2, float* __restrict__ h2)
{
    int bid = xcd_swz(blockIdx.x, gridDim.x);
    int t = threadIdx.x;
    int wv = t >> 6, l = t & 63;
    int n = bid * 4 + wv;
    if (n >= NN) return;
    int half = l >> 5, c = l & 31;
    const float* base = OUT2 + (size_t)n * 528;
    float q0 = base[c], q1 = base[32 + c], q2 = base[64 + c], q3 = base[96 + c];
    float p2 = (c < 16) ? base[512 + c] : 0.f;
    float av0 = 0.f, av1 = 0.f, av2 = 0.f, av3 = 0.f, ae = 0.f, denom = 0.f;
    int e0 = row_start[n], e1 = row_start[n + 1];
    for (int idx = e0 + half; idx < e1; idx += 2) {
        int s = se[idx];
        const _Float16* kb = KVh + (size_t)s * 256;
        float k0 = (float)kb[c], k1 = (float)kb[32 + c];
        float k2 = (float)kb[64 + c], k3 = (float)kb[96 + c];
        float v0 = (float)kb[128 + c], v1 = (float)kb[160 + c];
        float v2 = (float)kb[192 + c], v3 = (float)kb[224 + c];
        float eav = (c < 16) ? eac[(size_t)idx * 16 + c] : 0.f;
        float part = q0 * k0 + q1 * k1 + q2 * k2 + q3 * k3 + p2 * eav;
        part += __shfl_xor(part, 1, 64);
        part += __shfl_xor(part, 2, 64);
        part += __shfl_xor(part, 4, 64);
        part += __shfl_xor(part, 8, 64);
        part += __shfl_xor(part, 16, 64);
        float w = __expf(part * 0.08838834764831845f);  // 1/sqrt(128)
        denom += w;
        av0 += w * v0; av1 += w * v1; av2 += w * v2; av3 += w * v3;
        ae += w * eav;
    }
    denom += __shfl_xor(denom, 32, 64);
    av0 += __shfl_xor(av0, 32, 64);
    av1 += __shfl_xor(av1, 32, 64);
    av2 += __shfl_xor(av2, 32, 64);
    av3 += __shfl_xor(av3, 32, 64);
    ae  += __shfl_xor(ae, 32, 64);
    float inv = (denom > 0.f) ? 1.f / denom : 0.f;
    float t0 = 0.f, t1 = 0.f, t2 = 0.f, t3 = 0.f;
    #pragma unroll
    for (int d = 0; d < 16; ++d) {
        float aed = __shfl(ae, d, 64);
        t0 += aed * We2[d * 128 + c];
        t1 += aed * We2[d * 128 + 32 + c];
        t2 += aed * We2[d * 128 + 64 + c];
        t3 += aed * We2[d * 128 + 96 + c];
    }
    if (half == 0) {
        float* hp = h2 + (size_t)n * 128;
        hp[c]      = (av0 + t0) * inv + base[384 + c];
        hp[32 + c] = (av1 + t1) * inv + base[416 + c];
        hp[64 + c] = (av2 + t2) * inv + base[448 + c];
        hp[96 + c] = (av3 + t3) * inv + base[480 + c];
    }
}

// ---------------------------------------------------------------------------
// pooling: sorted batch -> register-accumulated flushes
// ---------------------------------------------------------------------------
__global__ void pool_kernel(const float* __restrict__ h2, const int* __restrict__ batch,
                            float* __restrict__ sums, float* __restrict__ cnt)
{
    int t = threadIdx.x;
    int c = t & 127, half = t >> 7;
    int n0 = blockIdx.x * 64;
    float acc = 0.f, cacc = 0.f;
    int curg = -1;
    for (int r = half; r < 64; r += 2) {
        int n = n0 + r;
        if (n >= NN) break;
        int g = batch[n];
        if (g != curg) {
            if (curg >= 0) {
                atomicAdd(&sums[curg * 128 + c], acc);
                if (c == 0) atomicAdd(&cnt[curg], cacc);
            }
            curg = g; acc = 0.f; cacc = 0.f;
        }
        acc += h2[(size_t)n * 128 + c];
        cacc += 1.f;
    }
    if (curg >= 0) {
        atomicAdd(&sums[curg * 128 + c], acc);
        if (c == 0) atomicAdd(&cnt[curg], cacc);
    }
}

// Gp[g,c] = b1[c] + sum_m pool[g,m] * W1[272+m, c]
__global__ void gp_kernel(const float* __restrict__ sums, const float* __restrict__ cnt,
                          const float* __restrict__ W1, const float* __restrict__ b1,
                          float* __restrict__ Gp)
{
    __shared__ float pr[128];
    int g = blockIdx.x, c = threadIdx.x;
    float inv = 1.f / fmaxf(cnt[g], 1.f);
    pr[c] = sums[g * 128 + c] * inv;
    __syncthreads();
    float acc = b1[c];
    for (int m = 0; m < 128; ++m) acc += pr[m] * W1[(272 + m) * 128 + c];
    Gp[g * 128 + c] = acc;
}

// ---------------------------------------------------------------------------
// final: half-wave per CSR slot; lane owns 4 CONTIGUOUS cols [4c,4c+4).
// hid = A[s] + B[d] + Gp[g] + eaW[idx]; relu; dot W2. Pure gather+add.
// ---------------------------------------------------------------------------
__global__ void edge_out_kernel(const _Float16* __restrict__ ABh, const float* __restrict__ Gp,
                                const int4* __restrict__ ed4, const _Float16* __restrict__ eaWh,
                                const float* __restrict__ W2, const float* __restrict__ b2,
                                float* __restrict__ out)
{
    int t = threadIdx.x;
    int wv = t >> 6, l = t & 63;
    int half = l >> 5, c = l & 31;
    float4 w2r = *(const float4*)(W2 + 4 * c);
    float bias2 = b2[0];
    int bid = xcd_swz(blockIdx.x, gridDim.x);
    int base = bid * 128 + wv * 32;            // NE == gridDim*128 exactly
    for (int it = 0; it < 16; ++it) {
        int idx = base + it * 2 + half;
        int4 q4 = ed4[idx];
        int e = q4.x, s = q4.y, d = q4.z, g = q4.w;
        h16x4 As = *(const h16x4*)(ABh + (size_t)s * 256 + 4 * c);
        h16x4 Bd = *(const h16x4*)(ABh + (size_t)d * 256 + 128 + 4 * c);
        h16x4 ew = *(const h16x4*)(eaWh + (size_t)idx * 128 + 4 * c);
        float4 Gg = *(const float4*)(Gp + g * 128 + 4 * c);
        float h0 = fmaxf((float)As[0] + (float)Bd[0] + Gg.x + (float)ew[0], 0.f);
        float h1 = fmaxf((float)As[1] + (float)Bd[1] + Gg.y + (float)ew[1], 0.f);
        float h2 = fmaxf((float)As[2] + (float)Bd[2] + Gg.z + (float)ew[2], 0.f);
        float h3 = fmaxf((float)As[3] + (float)Bd[3] + Gg.w + (float)ew[3], 0.f);
        float r = h0 * w2r.x + h1 * w2r.y + h2 * w2r.z + h3 * w2r.w;
        r += __shfl_xor(r, 1, 64);
        r += __shfl_xor(r, 2, 64);
        r += __shfl_xor(r, 4, 64);
        r += __shfl_xor(r, 8, 64);
        r += __shfl_xor(r, 16, 64);
        if (c == 0) out[e] = r + bias2;
    }
}

// ---------------------------------------------------------------------------
extern "C" void kernel_launch(void* const* d_in, const int* in_sizes, int n_in,
                              void* d_out, int out_size, void* d_ws, size_t ws_size,
                              hipStream_t stream)
{
    const float* x   = (const float*)d_in[0];
    const int* ei    = (const int*)d_in[1];
    const float* ea  = (const float*)d_in[2];
    const int* batch = (const int*)d_in[3];
    const float* Wq1 = (const float*)d_in[4];  const float* bq1 = (const float*)d_in[5];
    const float* Wk1 = (const float*)d_in[6];  const float* bk1 = (const float*)d_in[7];
    const float* Wv1 = (const float*)d_in[8];  const float* bv1 = (const float*)d_in[9];
    const float* We1 = (const float*)d_in[10];
    const float* Ws1 = (const float*)d_in[11]; const float* bs1 = (const float*)d_in[12];
    const float* Wq2 = (const float*)d_in[13]; const float* bq2 = (const float*)d_in[14];
    const float* Wk2 = (const float*)d_in[15]; const float* bk2 = (const float*)d_in[16];
    const float* Wv2 = (const float*)d_in[17]; const float* bv2 = (const float*)d_in[18];
    const float* We2 = (const float*)d_in[19];
    const float* Ws2 = (const float*)d_in[20]; const float* bs2 = (const float*)d_in[21];
    const float* W1  = (const float*)d_in[22]; const float* b1  = (const float*)d_in[23];
    const float* W2  = (const float*)d_in[24]; const float* b2  = (const float*)d_in[25];

    const int* src = ei;
    const int* dst = ei + NE;

    float* ws = (float*)d_ws;
    size_t off = 0;
    float* OUT  = ws + off; off += (size_t)NN * 640;  // OUT1/OUT2; later ABh + eaWh (exact fit)
    float* h1   = ws + off; off += (size_t)NN * 128;
    float* h2   = ws + off; off += (size_t)NN * 128;
    float* eac  = ws + off; off += (size_t)NE * 16;
    _Float16* KVh = (_Float16*)(ws + off); off += (size_t)NN * 128;  // N x 256 half
    float* sums = ws + off; off += NG * 128;
    float* cntf = ws + off; off += NG;
    float* Gp   = ws + off; off += NG * 128;
    float* Wp1  = ws + off; off += 64 * 128;
    float* Wp2  = ws + off; off += 128 * 16;
    float* bcat1 = ws + off; off += 640;
    float* bcat2 = ws + off; off += 528;
    __bf16* pk  = (__bf16*)(ws + off); off += 284 * 1024 / 2;  // 284 blocks x 1024 bf16
    int* cnt_arr   = (int*)(ws + off); off += NN;
    int* row_start = (int*)(ws + off); off += NN + 1;
    int* cursor    = (int*)(ws + off); off += NN;
    int* se        = (int*)(ws + off); off += NE;
    int* bsum      = (int*)(ws + off); off += 64;
    int* boff      = (int*)(ws + off); off += 64;
    off = (off + 3) & ~(size_t)3;                      // 16B align for int4
    int4* ed4      = (int4*)(ws + off); off += (size_t)NE * 4;
    // alias: after agg2, OUT region = ABh (NN*256 half) ++ eaWh (NE*128 half) = NN*640 floats
    _Float16* ABh  = (_Float16*)OUT;
    _Float16* eaWh = (_Float16*)(OUT + (size_t)NN * 128);

    hipMemsetAsync(cnt_arr, 0, NN * sizeof(int), stream);
    hipMemsetAsync(sums, 0, (NG * 128 + NG) * sizeof(float), stream);

    prep_kernel<<<45, 256, 0, stream>>>(Wq1, bq1, bk1, bv1, bs1, We1,
                                        Wq2, bq2, bk2, bv2, bs2, We2,
                                        Wp1, Wp2, bcat1, bcat2);
    pack_kernel<<<284, 256, 0, stream>>>(Wq1, Wk1, Wv1, Ws1, Wp1,
                                         Wq2, Wk2, Wv2, Ws2, Wp2, W1, pk);
    count_kernel<<<(NE + 255) / 256, 256, 0, stream>>>(dst, cnt_arr);
    scanA_kernel<<<SCAN_B, 1024, 0, stream>>>(cnt_arr, row_start, bsum);
    scanB_kernel<<<1, 64, 0, stream>>>(bsum, boff);
    scanC_kernel<<<SCAN_B, 1024, 0, stream>>>(row_start, boff, cursor);
    scatter_kernel<<<(NE + 255) / 256, 256, 0, stream>>>(src, dst, batch, cursor, ed4, se);
    eacopy_kernel<<<NE * 16 / 256, 256, 0, stream>>>(ed4, ea, eac);

    dim3 g1((NN + 127) / 128, 4);
    mfma_gemm_kernel<64, 40, 4, true, 128, 384><<<g1, 256, 0, stream>>>(
        x, pk, bcat1, OUT, 640, KVh);
    agg1_kernel<<<(NN + 3) / 4, 256, 0, stream>>>(OUT, KVh, row_start, se, eac, We1, h1);
    dim3 g2((NN + 127) / 128, 4);
    mfma_gemm_kernel<128, 33, 4, true, 128, 384><<<g2, 256, 0, stream>>>(
        h1, pk + (size_t)80 * 1024, bcat2, OUT, 528, KVh);
    agg2_kernel<<<(NN + 3) / 4, 256, 0, stream>>>(OUT, KVh, row_start, se, eac, We2, h2);
    pool_kernel<<<(NN + 63) / 64, 256, 0, stream>>>(h2, batch, sums, cntf);
    gp_kernel<<<NG, 128, 0, stream>>>(sums, cntf, W1, b1, Gp);
    dim3 g3((NN + 127) / 128, 2);
    mfma_gemm_kernel<128, 16, 2, false, 0, 256><<<g3, 256, 0, stream>>>(
        h2, pk + (size_t)212 * 1024, nullptr, nullptr, 0, ABh);
    eaw_kernel<<<NE / 128, 256, 0, stream>>>(eac, pk + (size_t)276 * 1024, eaWh);
    edge_out_kernel<<<NE / 128, 256, 0, stream>>>(ABh, Gp, ed4, eaWh,
                                                  W2, b2, (float*)d_out);
}

// Round 10
// 431.127 us; speedup vs baseline: 1.0589x; 1.0075x over previous
//
#include <hip/hip_runtime.h>
#include <math.h>

#define NN 50000
#define NE 400000
#define NG 128
#define SCAN_B 49   // ceil(NN/1024)

typedef __bf16 bf16x8 __attribute__((ext_vector_type(8)));
typedef float f32x4 __attribute__((ext_vector_type(4)));
typedef _Float16 h16x2 __attribute__((ext_vector_type(2)));
typedef _Float16 h16x4 __attribute__((ext_vector_type(4)));

// bijective XCD-chunked swizzle (m204): each XCD gets a contiguous chunk
__device__ __forceinline__ int xcd_swz(int bid, int nwg)
{
    int q = nwg >> 3, r = nwg & 7;
    int xcd = bid & 7, off = bid >> 3;
    return (xcd < r ? xcd * (q + 1) : r * (q + 1) + (xcd - r) * q) + off;
}

// ---------------------------------------------------------------------------
// prep: fused weights Wp1[64,128], Wp2[128,16]; concatenated biases
// ---------------------------------------------------------------------------
__global__ void prep_kernel(const float* __restrict__ Wq1, const float* __restrict__ bq1,
                            const float* __restrict__ bk1, const float* __restrict__ bv1,
                            const float* __restrict__ bs1, const float* __restrict__ We1,
                            const float* __restrict__ Wq2, const float* __restrict__ bq2,
                            const float* __restrict__ bk2, const float* __restrict__ bv2,
                            const float* __restrict__ bs2, const float* __restrict__ We2,
                            float* __restrict__ Wp1, float* __restrict__ Wp2,
                            float* __restrict__ bcat1, float* __restrict__ bcat2)
{
    int idx = blockIdx.x * blockDim.x + threadIdx.x;
    if (idx < 8192) {                       // Wp1[64,128]
        int m = idx >> 7, c = idx & 127;
        int h = c >> 4, d = c & 15;
        float s = 0.f;
        #pragma unroll
        for (int j = 0; j < 16; ++j)
            s += Wq1[m * 128 + h * 16 + j] * We1[d * 128 + h * 16 + j];
        Wp1[idx] = s;
    } else if (idx < 8320) {                // bp1 -> bcat1[512..640)
        int c = idx - 8192;
        int h = c >> 4, d = c & 15;
        float s = 0.f;
        #pragma unroll
        for (int j = 0; j < 16; ++j)
            s += bq1[h * 16 + j] * We1[d * 128 + h * 16 + j];
        bcat1[512 + c] = s;
    } else if (idx < 10368) {               // Wp2[128,16]
        int i = idx - 8320;
        int m = i >> 4, d = i & 15;
        float s = 0.f;
        for (int j = 0; j < 128; ++j)
            s += Wq2[m * 128 + j] * We2[d * 128 + j];
        Wp2[m * 16 + d] = s;
    } else if (idx < 10384) {               // bp2 -> bcat2[512..528)
        int d = idx - 10368;
        float s = 0.f;
        for (int j = 0; j < 128; ++j)
            s += bq2[j] * We2[d * 128 + j];
        bcat2[512 + d] = s;
    } else if (idx < 10896) {               // bcat1[0..512)
        int i = idx - 10384;
        int seg = i >> 7, c = i & 127;
        const float* b = (seg == 0) ? bq1 : (seg == 1) ? bk1 : (seg == 2) ? bv1 : bs1;
        bcat1[i] = b[c];
    } else if (idx < 11408) {               // bcat2[0..512)
        int i = idx - 10896;
        int seg = i >> 7, c = i & 127;
        const float* b = (seg == 0) ? bq2 : (seg == 1) ? bk2 : (seg == 2) ? bv2 : bs2;
        bcat2[i] = b[c];
    }
}

// ---------------------------------------------------------------------------
// pack: MFMA fragment-ready hi/lo bf16 weight blocks.
//   mat0: gemm1 Wcat[64,640]   blocks 0..79
//   mat1: gemm2 Wcat[128,528]  blocks 80..211
//   mat2: gemm3 Wcat[128,256]  blocks 212..275
//   mat3: W1c[16->32pad,128]   blocks 276..283 (for eaW GEMM)
// ---------------------------------------------------------------------------
__global__ void pack_kernel(const float* __restrict__ Wq1, const float* __restrict__ Wk1,
                            const float* __restrict__ Wv1, const float* __restrict__ Ws1,
                            const float* __restrict__ Wp1,
                            const float* __restrict__ Wq2, const float* __restrict__ Wk2,
                            const float* __restrict__ Wv2, const float* __restrict__ Ws2,
                            const float* __restrict__ Wp2,
                            const float* __restrict__ W1,
                            __bf16* __restrict__ pk)
{
    int b = blockIdx.x;
    int mat, kt, ct;
    if (b < 80)       { mat = 0; kt = b / 40;        ct = b % 40; }
    else if (b < 212) { mat = 1; kt = (b - 80) / 33; ct = (b - 80) % 33; }
    else if (b < 276) { mat = 2; kt = (b - 212) / 16; ct = (b - 212) % 16; }
    else              { mat = 3; kt = 0;             ct = b - 276; }
    __bf16* blkp = pk + (size_t)b * 1024;
    for (int item = threadIdx.x; item < 512; item += 256) {
        int lane = item >> 3, j = item & 7;
        int k = kt * 32 + (lane >> 4) * 8 + j;
        int col = ct * 16 + (lane & 15);
        float v;
        if (mat == 0) {
            int seg = col >> 7, cc = col & 127;
            const float* W = (seg == 0) ? Wq1 : (seg == 1) ? Wk1 : (seg == 2) ? Wv1
                             : (seg == 3) ? Ws1 : Wp1;
            v = W[k * 128 + cc];
        } else if (mat == 1) {
            if (col < 512) {
                int seg = col >> 7, cc = col & 127;
                const float* W = (seg == 0) ? Wq2 : (seg == 1) ? Wk2 : (seg == 2) ? Wv2 : Ws2;
                v = W[k * 128 + cc];
            } else {
                v = Wp2[k * 16 + (col - 512)];
            }
        } else if (mat == 2) {
            v = (col < 128) ? W1[k * 128 + col] : W1[(size_t)(128 + k) * 128 + (col - 128)];
        } else {
            v = (k < 16) ? W1[(size_t)(256 + k) * 128 + col] : 0.f;
        }
        __bf16 h = (__bf16)v;
        __bf16 lo = (__bf16)(v - (float)h);
        blkp[lane * 8 + j] = h;
        blkp[512 + lane * 8 + j] = lo;
    }
}

// ---------------------------------------------------------------------------
// CSR build by dst — count, 3-phase parallel scan, scatter, ea copy
// ---------------------------------------------------------------------------
__global__ void count_kernel(const int* __restrict__ dst, int* __restrict__ counts)
{
    int e = blockIdx.x * blockDim.x + threadIdx.x;
    if (e < NE) atomicAdd(&counts[dst[e]], 1);
}

__global__ void scanA_kernel(const int* __restrict__ counts,
                             int* __restrict__ row_start, int* __restrict__ bsum)
{
    __shared__ int lds[1024];
    int t = threadIdx.x, b = blockIdx.x;
    int i = b * 1024 + t;
    int v = (i < NN) ? counts[i] : 0;
    lds[t] = v;
    __syncthreads();
    for (int off = 1; off < 1024; off <<= 1) {
        int u = (t >= off) ? lds[t - off] : 0;
        __syncthreads();
        lds[t] += u;
        __syncthreads();
    }
    if (i < NN) row_start[i] = lds[t] - v;     // block-local exclusive
    if (t == 1023) bsum[b] = lds[1023];
}

__global__ void scanB_kernel(const int* __restrict__ bsum, int* __restrict__ boff)
{
    int t = threadIdx.x;  // 64 lanes
    int orig = (t < SCAN_B) ? bsum[t] : 0;
    int v = orig;
    #pragma unroll
    for (int off = 1; off < 64; off <<= 1) {
        int u = __shfl_up(v, off, 64);
        if (t >= off) v += u;
    }
    if (t < SCAN_B) boff[t] = v - orig;        // exclusive
}

__global__ void scanC_kernel(int* __restrict__ row_start, const int* __restrict__ boff,
                             int* __restrict__ cursor)
{
    int i = blockIdx.x * 1024 + threadIdx.x;
    if (i < NN) {
        int rs = row_start[i] + boff[blockIdx.x];
        row_start[i] = rs;
        cursor[i] = rs;
    }
    if (i == 0) row_start[NN] = NE;
}

__global__ void scatter_kernel(const int* __restrict__ src, const int* __restrict__ dst,
                               const int* __restrict__ batch,
                               int* __restrict__ cursor, int4* __restrict__ ed4,
                               int* __restrict__ se)
{
    int e = blockIdx.x * blockDim.x + threadIdx.x;
    if (e < NE) {
        int d = dst[e];
        int s = src[e];
        int p = atomicAdd(&cursor[d], 1);
        ed4[p] = make_int4(e, s, d, batch[s]);
        se[p] = s;
    }
}

__global__ void eacopy_kernel(const int4* __restrict__ ed4, const float* __restrict__ ea,
                              float* __restrict__ eac)
{
    int g = blockIdx.x * blockDim.x + threadIdx.x;  // NE*16 threads
    int idx = g >> 4, c = g & 15;
    eac[g] = ea[(size_t)ed4[idx].x * 16 + c];
}

// ---------------------------------------------------------------------------
// MFMA GEMM, split-bf16 3-term. Columns in [CLO,CHI) go to fp16 aux buffer
// (width CHI-CLO); other columns to fp32 out (stride ldo).
// Column tiles split across blockIdx.y (NCG groups) for occupancy.
// ---------------------------------------------------------------------------
__device__ __forceinline__ void load_split(const float* ap, bool ok,
                                           bf16x8& hv, bf16x8& lv)
{
    float av[8];
    if (ok) {
        float4 f0 = *(const float4*)ap;
        float4 f1 = *(const float4*)(ap + 4);
        av[0] = f0.x; av[1] = f0.y; av[2] = f0.z; av[3] = f0.w;
        av[4] = f1.x; av[5] = f1.y; av[6] = f1.z; av[7] = f1.w;
    } else {
        #pragma unroll
        for (int j = 0; j < 8; ++j) av[j] = 0.f;
    }
    #pragma unroll
    for (int j = 0; j < 8; ++j) {
        __bf16 h = (__bf16)av[j];
        hv[j] = h;
        lv[j] = (__bf16)(av[j] - (float)h);
    }
}

template<int KD, int NCT, int NCG, bool BIAS, int CLO, int CHI>
__global__ void mfma_gemm_kernel(const float* __restrict__ A, const __bf16* __restrict__ pk,
                                 const float* __restrict__ bias, float* __restrict__ out,
                                 int ldo, _Float16* __restrict__ auxh)
{
    constexpr int NKT = KD / 32;
    constexpr int AUXW = CHI - CLO;
    constexpr int CPG = (NCT + NCG - 1) / NCG;
    int cg = blockIdx.y;
    int ct0 = cg * CPG;
    int ct1 = (ct0 + CPG < NCT) ? ct0 + CPG : NCT;
    int t = threadIdx.x, w = t >> 6, l = t & 63;
    int rbase = blockIdx.x * 128 + w * 32;
    int lr = l & 15, kq = l >> 4;
    int r0 = rbase + lr, r1 = rbase + 16 + lr;
    bool ok0 = r0 < NN, ok1 = r1 < NN;
    bf16x8 ah0[NKT], al0[NKT], ah1[NKT], al1[NKT];
    #pragma unroll
    for (int kt = 0; kt < NKT; ++kt) {
        load_split(A + (size_t)r0 * KD + kt * 32 + kq * 8, ok0, ah0[kt], al0[kt]);
        load_split(A + (size_t)r1 * KD + kt * 32 + kq * 8, ok1, ah1[kt], al1[kt]);
    }
    for (int ct = ct0; ct < ct1; ++ct) {
        float b = BIAS ? bias[ct * 16 + lr] : 0.f;
        f32x4 acc0 = {b, b, b, b};
        f32x4 acc1 = {b, b, b, b};
        const __bf16* blk = pk + (size_t)ct * 1024;
        #pragma unroll
        for (int kt = 0; kt < NKT; ++kt) {
            bf16x8 bh = *(const bf16x8*)(blk + (size_t)kt * NCT * 1024 + l * 8);
            bf16x8 bl = *(const bf16x8*)(blk + (size_t)kt * NCT * 1024 + 512 + l * 8);
            acc0 = __builtin_amdgcn_mfma_f32_16x16x32_bf16(al0[kt], bh, acc0, 0, 0, 0);
            acc1 = __builtin_amdgcn_mfma_f32_16x16x32_bf16(al1[kt], bh, acc1, 0, 0, 0);
            acc0 = __builtin_amdgcn_mfma_f32_16x16x32_bf16(ah0[kt], bl, acc0, 0, 0, 0);
            acc1 = __builtin_amdgcn_mfma_f32_16x16x32_bf16(ah1[kt], bl, acc1, 0, 0, 0);
            acc0 = __builtin_amdgcn_mfma_f32_16x16x32_bf16(ah0[kt], bh, acc0, 0, 0, 0);
            acc1 = __builtin_amdgcn_mfma_f32_16x16x32_bf16(ah1[kt], bh, acc1, 0, 0, 0);
        }
        int col = ct * 16 + lr;
        bool inAux = (col >= CLO) && (col < CHI);
        #pragma unroll
        for (int i = 0; i < 4; ++i) {
            int ra = rbase + kq * 4 + i;
            int rb = ra + 16;
            if (ra < NN) {
                if (inAux) auxh[(size_t)ra * AUXW + (col - CLO)] = (_Float16)acc0[i];
                else       out[(size_t)ra * ldo + col] = acc0[i];
            }
            if (rb < NN) {
                if (inAux) auxh[(size_t)rb * AUXW + (col - CLO)] = (_Float16)acc1[i];
                else       out[(size_t)rb * ldo + col] = acc1[i];
            }
        }
    }
}

// ---------------------------------------------------------------------------
// eaw: eaWh[E,128] = eac[E,16] @ W1c (split-bf16, K padded to 32). fp16 out.
// Wave = 32 rows; 4 waves/block -> 128 rows/block; NE/128 blocks exactly.
// ---------------------------------------------------------------------------
__global__ void eaw_kernel(const float* __restrict__ eac, const __bf16* __restrict__ pk,
                           _Float16* __restrict__ eaWh)
{
    int t = threadIdx.x, w = t >> 6, l = t & 63;
    int rbase = blockIdx.x * 128 + w * 32;
    int lr = l & 15, kq = l >> 4;
    bf16x8 ah0, al0, ah1, al1;
    if (kq < 2) {
        load_split(eac + (size_t)(rbase + lr) * 16 + kq * 8, true, ah0, al0);
        load_split(eac + (size_t)(rbase + 16 + lr) * 16 + kq * 8, true, ah1, al1);
    } else {
        #pragma unroll
        for (int j = 0; j < 8; ++j) { ah0[j] = (__bf16)0.f; al0[j] = (__bf16)0.f;
                                      ah1[j] = (__bf16)0.f; al1[j] = (__bf16)0.f; }
    }
    #pragma unroll
    for (int ct = 0; ct < 8; ++ct) {
        f32x4 acc0 = {0.f, 0.f, 0.f, 0.f};
        f32x4 acc1 = {0.f, 0.f, 0.f, 0.f};
        const __bf16* blk = pk + (size_t)ct * 1024;
        bf16x8 bh = *(const bf16x8*)(blk + l * 8);
        bf16x8 bl = *(const bf16x8*)(blk + 512 + l * 8);
        acc0 = __builtin_amdgcn_mfma_f32_16x16x32_bf16(al0, bh, acc0, 0, 0, 0);
        acc1 = __builtin_amdgcn_mfma_f32_16x16x32_bf16(al1, bh, acc1, 0, 0, 0);
        acc0 = __builtin_amdgcn_mfma_f32_16x16x32_bf16(ah0, bl, acc0, 0, 0, 0);
        acc1 = __builtin_amdgcn_mfma_f32_16x16x32_bf16(ah1, bl, acc1, 0, 0, 0);
        acc0 = __builtin_amdgcn_mfma_f32_16x16x32_bf16(ah0, bh, acc0, 0, 0, 0);
        acc1 = __builtin_amdgcn_mfma_f32_16x16x32_bf16(ah1, bh, acc1, 0, 0, 0);
        int col = ct * 16 + lr;
        #pragma unroll
        for (int i = 0; i < 4; ++i) {
            int ra = rbase + kq * 4 + i;
            eaWh[(size_t)ra * 128 + col] = (_Float16)acc0[i];
            eaWh[(size_t)(ra + 16) * 128 + col] = (_Float16)acc1[i];
        }
    }
}

// ---------------------------------------------------------------------------
// agg1: wave per node. f32 OUT1 row [Q|-|-|S|P] stride 640; fp16 KVh [K|V] 256.
// lane = h*8 + p; lane owns j = 2p, 2p+1 of head h. 2-way edge unroll.
// ---------------------------------------------------------------------------
__global__ void agg1_kernel(const float* __restrict__ OUT1, const _Float16* __restrict__ KVh,
                            const int* __restrict__ row_start,
                            const int* __restrict__ se, const float* __restrict__ eac,
                            const float* __restrict__ We1, float* __restrict__ h1)
{
    __shared__ float we[16 * 128];
    int t = threadIdx.x;
    for (int i = t; i < 2048; i += 256) we[i] = We1[i];
    __syncthreads();
    int bid = xcd_swz(blockIdx.x, gridDim.x);
    int wv = t >> 6, l = t & 63;
    int n = bid * 4 + wv;
    if (n >= NN) return;
    int h = l >> 3, p = l & 7;
    int j0 = p * 2;
    const float* qb = OUT1 + (size_t)n * 640;
    float2 q = *(const float2*)(qb + h * 16 + j0);
    float2 P = *(const float2*)(qb + 512 + h * 16 + j0);
    float2 accv = make_float2(0.f, 0.f), acce = make_float2(0.f, 0.f);
    float denom = 0.f;
    int e0 = row_start[n], e1 = row_start[n + 1];
    int idx = e0;
    for (; idx + 1 < e1; idx += 2) {
        int sA = se[idx], sB = se[idx + 1];
        const _Float16* kvA = KVh + (size_t)sA * 256;
        const _Float16* kvB = KVh + (size_t)sB * 256;
        h16x2 kAh = *(const h16x2*)(kvA + h * 16 + j0);
        h16x2 vAh = *(const h16x2*)(kvA + 128 + h * 16 + j0);
        float2 eA = *(const float2*)(eac + (size_t)idx * 16 + j0);
        h16x2 kBh = *(const h16x2*)(kvB + h * 16 + j0);
        h16x2 vBh = *(const h16x2*)(kvB + 128 + h * 16 + j0);
        float2 eB = *(const float2*)(eac + (size_t)(idx + 1) * 16 + j0);
        float pa = q.x * (float)kAh[0] + q.y * (float)kAh[1] + P.x * eA.x + P.y * eA.y;
        float pb = q.x * (float)kBh[0] + q.y * (float)kBh[1] + P.x * eB.x + P.y * eB.y;
        pa += __shfl_xor(pa, 1, 64); pb += __shfl_xor(pb, 1, 64);
        pa += __shfl_xor(pa, 2, 64); pb += __shfl_xor(pb, 2, 64);
        pa += __shfl_xor(pa, 4, 64); pb += __shfl_xor(pb, 4, 64);
        float wA = __expf(pa * 0.25f);
        float wB = __expf(pb * 0.25f);
        denom += wA + wB;
        accv.x += wA * (float)vAh[0] + wB * (float)vBh[0];
        accv.y += wA * (float)vAh[1] + wB * (float)vBh[1];
        acce.x += wA * eA.x + wB * eB.x;
        acce.y += wA * eA.y + wB * eB.y;
    }
    if (idx < e1) {
        int s = se[idx];
        const _Float16* kvb = KVh + (size_t)s * 256;
        h16x2 kk = *(const h16x2*)(kvb + h * 16 + j0);
        h16x2 vv = *(const h16x2*)(kvb + 128 + h * 16 + j0);
        float2 ee = *(const float2*)(eac + (size_t)idx * 16 + j0);
        float part = q.x * (float)kk[0] + q.y * (float)kk[1] + P.x * ee.x + P.y * ee.y;
        part += __shfl_xor(part, 1, 64);
        part += __shfl_xor(part, 2, 64);
        part += __shfl_xor(part, 4, 64);
        float w = __expf(part * 0.25f);
        denom += w;
        accv.x += w * (float)vv[0]; accv.y += w * (float)vv[1];
        acce.x += w * ee.x; acce.y += w * ee.y;
    }
    float inv = (denom > 0.f) ? 1.f / denom : 0.f;
    float es0 = 0.f, es1 = 0.f;
    int gbase = h * 8;
    #pragma unroll
    for (int dd = 0; dd < 8; ++dd) {
        float a0 = __shfl(acce.x, gbase + dd, 64);
        float a1 = __shfl(acce.y, gbase + dd, 64);
        es0 += a0 * we[(2 * dd) * 128 + h * 16 + j0]     + a1 * we[(2 * dd + 1) * 128 + h * 16 + j0];
        es1 += a0 * we[(2 * dd) * 128 + h * 16 + j0 + 1] + a1 * we[(2 * dd + 1) * 128 + h * 16 + j0 + 1];
    }
    float2 sk = *(const float2*)(qb + 384 + h * 16 + j0);
    float o0 = (accv.x + es0) * inv + sk.x;
    float o1 = (accv.y + es1) * inv + sk.y;
    o0 = (o0 > 0.f) ? o0 : 0.01f * o0;
    o1 = (o1 > 0.f) ? o1 : 0.01f * o1;
    *(float2*)(h1 + (size_t)n * 128 + h * 16 + j0) = make_float2(o0, o1);
}

// ---------------------------------------------------------------------------
// agg2: wave per node, half-wave per edge. f32 OUT2 [Q|-|-|S|P2] stride 528;
// fp16 KVh [K|V] 256. lane = half*32 + c; lane owns dims {c,c+32,c+64,c+96}.
// ---------------------------------------------------------------------------
__global__ void agg2_kernel(const float* __restrict__ OUT2, const _Float16* __restrict__ KVh,
                            const int* __restrict__ row_start,
                            const int* __restrict__ se, const float* __restrict__ eac,
                            const float* __restrict__ We2, float* __restrict__ h2)
{
    int bid = xcd_swz(blockIdx.x, gridDim.x);
    int t = threadIdx.x;
    int wv = t >> 6, l = t & 63;
    int n = bid * 4 + wv;
    if (n >= NN) return;
    int half = l >> 5, c = l & 31;
    const float* base = OUT2 + (size_t)n * 528;
    float q0 = base[c], q1 = base[32 + c], q2 = base[64 + c], q3 = base[96 + c];
    float p2 = (c < 16) ? base[512 + c] : 0.f;
    float av0 = 0.f, av1 = 0.f, av2 = 0.f, av3 = 0.f, ae = 0.f, denom = 0.f;
    int e0 = row_start[n], e1 = row_start[n + 1];
    for (int idx = e0 + half; idx < e1; idx += 2) {
        int s = se[idx];
        const _Float16* kb = KVh + (size_t)s * 256;
        float k0 = (float)kb[c], k1 = (float)kb[32 + c];
        float k2 = (float)kb[64 + c], k3 = (float)kb[96 + c];
        float v0 = (float)kb[128 + c], v1 = (float)kb[160 + c];
        float v2 = (float)kb[192 + c], v3 = (float)kb[224 + c];
        float eav = (c < 16) ? eac[(size_t)idx * 16 + c] : 0.f;
        float part = q0 * k0 + q1 * k1 + q2 * k2 + q3 * k3 + p2 * eav;
        part += __shfl_xor(part, 1, 64);
        part += __shfl_xor(part, 2, 64);
        part += __shfl_xor(part, 4, 64);
        part += __shfl_xor(part, 8, 64);
        part += __shfl_xor(part, 16, 64);
        float w = __expf(part * 0.08838834764831845f);  // 1/sqrt(128)
        denom += w;
        av0 += w * v0; av1 += w * v1; av2 += w * v2; av3 += w * v3;
        ae += w * eav;
    }
    denom += __shfl_xor(denom, 32, 64);
    av0 += __shfl_xor(av0, 32, 64);
    av1 += __shfl_xor(av1, 32, 64);
    av2 += __shfl_xor(av2, 32, 64);
    av3 += __shfl_xor(av3, 32, 64);
    ae  += __shfl_xor(ae, 32, 64);
    float inv = (denom > 0.f) ? 1.f / denom : 0.f;
    float t0 = 0.f, t1 = 0.f, t2 = 0.f, t3 = 0.f;
    #pragma unroll
    for (int d = 0; d < 16; ++d) {
        float aed = __shfl(ae, d, 64);
        t0 += aed * We2[d * 128 + c];
        t1 += aed * We2[d * 128 + 32 + c];
        t2 += aed * We2[d * 128 + 64 + c];
        t3 += aed * We2[d * 128 + 96 + c];
    }
    if (half == 0) {
        float* hp = h2 + (size_t)n * 128;
        hp[c]      = (av0 + t0) * inv + base[384 + c];
        hp[32 + c] = (av1 + t1) * inv + base[416 + c];
        hp[64 + c] = (av2 + t2) * inv + base[448 + c];
        hp[96 + c] = (av3 + t3) * inv + base[480 + c];
    }
}

// ---------------------------------------------------------------------------
// pooling: sorted batch -> register-accumulated flushes
// ---------------------------------------------------------------------------
__global__ void pool_kernel(const float* __restrict__ h2, const int* __restrict__ batch,
                            float* __restrict__ sums, float* __restrict__ cnt)
{
    int t = threadIdx.x;
    int c = t & 127, half = t >> 7;
    int n0 = blockIdx.x * 64;
    float acc = 0.f, cacc = 0.f;
    int curg = -1;
    for (int r = half; r < 64; r += 2) {
        int n = n0 + r;
        if (n >= NN) break;
        int g = batch[n];
        if (g != curg) {
            if (curg >= 0) {
                atomicAdd(&sums[curg * 128 + c], acc);
                if (c == 0) atomicAdd(&cnt[curg], cacc);
            }
            curg = g; acc = 0.f; cacc = 0.f;
        }
        acc += h2[(size_t)n * 128 + c];
        cacc += 1.f;
    }
    if (curg >= 0) {
        atomicAdd(&sums[curg * 128 + c], acc);
        if (c == 0) atomicAdd(&cnt[curg], cacc);
    }
}

// Gp[g,c] = b1[c] + sum_m pool[g,m] * W1[272+m, c]
__global__ void gp_kernel(const float* __restrict__ sums, const float* __restrict__ cnt,
                          const float* __restrict__ W1, const float* __restrict__ b1,
                          float* __restrict__ Gp)
{
    __shared__ float pr[128];
    int g = blockIdx.x, c = threadIdx.x;
    float inv = 1.f / fmaxf(cnt[g], 1.f);
    pr[c] = sums[g * 128 + c] * inv;
    __syncthreads();
    float acc = b1[c];
    for (int m = 0; m < 128; ++m) acc += pr[m] * W1[(272 + m) * 128 + c];
    Gp[g * 128 + c] = acc;
}

// ---------------------------------------------------------------------------
// final: half-wave per CSR slot; lane owns 4 CONTIGUOUS cols [4c,4c+4).
// hid = A[s] + B[d] + Gp[g] + eaW[idx]; relu; dot W2. Pure gather+add.
// ---------------------------------------------------------------------------
__global__ void edge_out_kernel(const _Float16* __restrict__ ABh, const float* __restrict__ Gp,
                                const int4* __restrict__ ed4, const _Float16* __restrict__ eaWh,
                                const float* __restrict__ W2, const float* __restrict__ b2,
                                float* __restrict__ out)
{
    int t = threadIdx.x;
    int wv = t >> 6, l = t & 63;
    int half = l >> 5, c = l & 31;
    float4 w2r = *(const float4*)(W2 + 4 * c);
    float bias2 = b2[0];
    int bid = xcd_swz(blockIdx.x, gridDim.x);
    int base = bid * 128 + wv * 32;            // NE == gridDim*128 exactly
    for (int it = 0; it < 16; ++it) {
        int idx = base + it * 2 + half;
        int4 q4 = ed4[idx];
        int e = q4.x, s = q4.y, d = q4.z, g = q4.w;
        h16x4 As = *(const h16x4*)(ABh + (size_t)s * 256 + 4 * c);
        h16x4 Bd = *(const h16x4*)(ABh + (size_t)d * 256 + 128 + 4 * c);
        h16x4 ew = *(const h16x4*)(eaWh + (size_t)idx * 128 + 4 * c);
        float4 Gg = *(const float4*)(Gp + g * 128 + 4 * c);
        float h0 = fmaxf((float)As[0] + (float)Bd[0] + Gg.x + (float)ew[0], 0.f);
        float h1 = fmaxf((float)As[1] + (float)Bd[1] + Gg.y + (float)ew[1], 0.f);
        float h2 = fmaxf((float)As[2] + (float)Bd[2] + Gg.z + (float)ew[2], 0.f);
        float h3 = fmaxf((float)As[3] + (float)Bd[3] + Gg.w + (float)ew[3], 0.f);
        float r = h0 * w2r.x + h1 * w2r.y + h2 * w2r.z + h3 * w2r.w;
        r += __shfl_xor(r, 1, 64);
        r += __shfl_xor(r, 2, 64);
        r += __shfl_xor(r, 4, 64);
        r += __shfl_xor(r, 8, 64);
        r += __shfl_xor(r, 16, 64);
        if (c == 0) out[e] = r + bias2;
    }
}

// ---------------------------------------------------------------------------
extern "C" void kernel_launch(void* const* d_in, const int* in_sizes, int n_in,
                              void* d_out, int out_size, void* d_ws, size_t ws_size,
                              hipStream_t stream)
{
    const float* x   = (const float*)d_in[0];
    const int* ei    = (const int*)d_in[1];
    const float* ea  = (const float*)d_in[2];
    const int* batch = (const int*)d_in[3];
    const float* Wq1 = (const float*)d_in[4];  const float* bq1 = (const float*)d_in[5];
    const float* Wk1 = (const float*)d_in[6];  const float* bk1 = (const float*)d_in[7];
    const float* Wv1 = (const float*)d_in[8];  const float* bv1 = (const float*)d_in[9];
    const float* We1 = (const float*)d_in[10];
    const float* Ws1 = (const float*)d_in[11]; const float* bs1 = (const float*)d_in[12];
    const float* Wq2 = (const float*)d_in[13]; const float* bq2 = (const float*)d_in[14];
    const float* Wk2 = (const float*)d_in[15]; const float* bk2 = (const float*)d_in[16];
    const float* Wv2 = (const float*)d_in[17]; const float* bv2 = (const float*)d_in[18];
    const float* We2 = (const float*)d_in[19];
    const float* Ws2 = (const float*)d_in[20]; const float* bs2 = (const float*)d_in[21];
    const float* W1  = (const float*)d_in[22]; const float* b1  = (const float*)d_in[23];
    const float* W2  = (const float*)d_in[24]; const float* b2  = (const float*)d_in[25];

    const int* src = ei;
    const int* dst = ei + NE;

    float* ws = (float*)d_ws;
    size_t off = 0;
    float* OUT  = ws + off; off += (size_t)NN * 640;  // OUT1/OUT2; later ABh + eaWh (exact fit)
    float* h1   = ws + off; off += (size_t)NN * 128;
    float* h2   = ws + off; off += (size_t)NN * 128;
    float* eac  = ws + off; off += (size_t)NE * 16;
    _Float16* KVh = (_Float16*)(ws + off); off += (size_t)NN * 128;  // N x 256 half
    float* sums = ws + off; off += NG * 128;
    float* cntf = ws + off; off += NG;
    float* Gp   = ws + off; off += NG * 128;
    float* Wp1  = ws + off; off += 64 * 128;
    float* Wp2  = ws + off; off += 128 * 16;
    float* bcat1 = ws + off; off += 640;
    float* bcat2 = ws + off; off += 528;
    __bf16* pk  = (__bf16*)(ws + off); off += 284 * 1024 / 2;  // 284 blocks x 1024 bf16
    int* cnt_arr   = (int*)(ws + off); off += NN;
    int* row_start = (int*)(ws + off); off += NN + 1;
    int* cursor    = (int*)(ws + off); off += NN;
    int* se        = (int*)(ws + off); off += NE;
    int* bsum      = (int*)(ws + off); off += 64;
    int* boff      = (int*)(ws + off); off += 64;
    off = (off + 3) & ~(size_t)3;                      // 16B align for int4
    int4* ed4      = (int4*)(ws + off); off += (size_t)NE * 4;
    // alias: after agg2, OUT region = ABh (NN*256 half) ++ eaWh (NE*128 half) = NN*640 floats
    _Float16* ABh  = (_Float16*)OUT;
    _Float16* eaWh = (_Float16*)(OUT + (size_t)NN * 128);

    hipMemsetAsync(cnt_arr, 0, NN * sizeof(int), stream);
    hipMemsetAsync(sums, 0, (NG * 128 + NG) * sizeof(float), stream);

    prep_kernel<<<45, 256, 0, stream>>>(Wq1, bq1, bk1, bv1, bs1, We1,
                                        Wq2, bq2, bk2, bv2, bs2, We2,
                                        Wp1, Wp2, bcat1, bcat2);
    pack_kernel<<<284, 256, 0, stream>>>(Wq1, Wk1, Wv1, Ws1, Wp1,
                                         Wq2, Wk2, Wv2, Ws2, Wp2, W1, pk);
    count_kernel<<<(NE + 255) / 256, 256, 0, stream>>>(dst, cnt_arr);
    scanA_kernel<<<SCAN_B, 1024, 0, stream>>>(cnt_arr, row_start, bsum);
    scanB_kernel<<<1, 64, 0, stream>>>(bsum, boff);
    scanC_kernel<<<SCAN_B, 1024, 0, stream>>>(row_start, boff, cursor);
    scatter_kernel<<<(NE + 255) / 256, 256, 0, stream>>>(src, dst, batch, cursor, ed4, se);
    eacopy_kernel<<<NE * 16 / 256, 256, 0, stream>>>(ed4, ea, eac);

    dim3 g1((NN + 127) / 128, 4);
    mfma_gemm_kernel<64, 40, 4, true, 128, 384><<<g1, 256, 0, stream>>>(
        x, pk, bcat1, OUT, 640, KVh);
    agg1_kernel<<<(NN + 3) / 4, 256, 0, stream>>>(OUT, KVh, row_start, se, eac, We1, h1);
    dim3 g2((NN + 127) / 128, 4);
    mfma_gemm_kernel<128, 33, 4, true, 128, 384><<<g2, 256, 0, stream>>>(
        h1, pk + (size_t)80 * 1024, bcat2, OUT, 528, KVh);
    agg2_kernel<<<(NN + 3) / 4, 256, 0, stream>>>(OUT, KVh, row_start, se, eac, We2, h2);
    pool_kernel<<<(NN + 63) / 64, 256, 0, stream>>>(h2, batch, sums, cntf);
    gp_kernel<<<NG, 128, 0, stream>>>(sums, cntf, W1, b1, Gp);
    dim3 g3((NN + 127) / 128, 2);
    mfma_gemm_kernel<128, 16, 2, false, 0, 256><<<g3, 256, 0, stream>>>(
        h2, pk + (size_t)212 * 1024, nullptr, nullptr, 0, ABh);
    eaw_kernel<<<NE / 128, 256, 0, stream>>>(eac, pk + (size_t)276 * 1024, eaWh);
    edge_out_kernel<<<NE / 128, 256, 0, stream>>>(ABh, Gp, ed4, eaWh,
                                                  W2, b2, (float*)d_out);
}